// Round 1
// baseline (3482.478 us; speedup 1.0000x reference)
//
#include <hip/hip_runtime.h>
#include <math.h>

// ---------------------------------------------------------------------------
// Model_31009663877809: fluid advection net forward, f32.
// Shapes: prev/next (4,64,260,260), texture (4,64,258,258), out (4,64,258,258)
// Pipeline: enc(4x4 s4)->corr(81 off)x2 -> [up2x+conv3x3+bn+relu]x2 + 1x1 head
//           -> helmholtz velocity stencils -> BFECC warp -> LN+MLP residual.
// Workspace peak: ~226.2 MB (floats), with region reuse.
// ---------------------------------------------------------------------------

#define NIMG 32          // B*G
#define HW 260
#define HWT 258
#define EG 65            // enc grid
#define EGP (EG*EG)      // 4225
#define DENC 128
#define PIX_T (HWT*HWT)  // 66564
#define PIX_H (HW*HW)    // 67600

// ---------------- enc_w transpose: wt[i*128+d] = w[d*128+i] -----------------
__global__ void k_wt(const float* __restrict__ w, float* __restrict__ wt) {
    int e = blockIdx.x * 256 + threadIdx.x;
    if (e < 128 * 128) {
        int d = e >> 7, i = e & 127;
        wt[i * 128 + d] = w[e];
    }
}

// ---------------- encoder: conv 4x4 stride 4, NHWC output -------------------
// grid (5, 65, 32), block 128. Each block: 16 consecutive xo for one (n, yo).
__global__ __launch_bounds__(128) void k_enc(
    const float* __restrict__ src,   // (4,64,260,260)
    const float* __restrict__ mul,   // (4,260,260)
    const float* __restrict__ wt,    // (128i,128d) transposed
    const float* __restrict__ bias,  // (128)
    float* __restrict__ out)         // (32,65,65,128) NHWC
{
    int xt = blockIdx.x;             // 0..4
    int yo = blockIdx.y;             // 0..64
    int n  = blockIdx.z;             // 0..31
    int bi = n >> 3, g = n & 7;
    int xo0 = xt * 16;
    __shared__ __align__(16) float patch[2048];  // [c*4+r][64 cols]
    int tid = threadIdx.x;
    const float* sbase = src + (size_t)(bi * 64 + g * 8) * PIX_H;
    const float* mbase = mul + (size_t)bi * PIX_H;
    int row0 = yo * 4, col0 = xo0 * 4;
    for (int e = tid; e < 2048; e += 128) {
        int c = e >> 8, r = (e >> 6) & 3, col = e & 63;
        int gc = col0 + col;
        float v = 0.f;
        if (gc < HW) {
            int off = (row0 + r) * HW + gc;
            v = sbase[(size_t)c * PIX_H + off] * mbase[off];
        }
        patch[e] = v;
    }
    __syncthreads();
    int d = tid;
    float acc[16];
    float bv = bias[d];
#pragma unroll
    for (int p = 0; p < 16; ++p) acc[p] = bv;
    const float4* p4 = (const float4*)patch;
    for (int j = 0; j < 32; ++j) {   // j = c*4 + ky
        float w0 = wt[(j * 4 + 0) * 128 + d];
        float w1 = wt[(j * 4 + 1) * 128 + d];
        float w2 = wt[(j * 4 + 2) * 128 + d];
        float w3 = wt[(j * 4 + 3) * 128 + d];
#pragma unroll
        for (int p = 0; p < 16; ++p) {
            float4 v = p4[j * 16 + p];
            acc[p] += w0 * v.x + w1 * v.y + w2 * v.z + w3 * v.w;
        }
    }
    size_t ob = ((size_t)(n * EG + yo) * EG + xo0) * 128 + d;
#pragma unroll
    for (int p = 0; p < 16; ++p)
        if (xo0 + p < EG) out[ob + (size_t)p * 128] = acc[p];
}

// ---------------- correlation ------------------------------------------------
// grid (18, 65, 32): bx = dy*2+xt. block 128. LDS rows padded to 132 floats.
__global__ __launch_bounds__(128) void k_corr(
    const float* __restrict__ f1,  // (32,65,65,128)
    const float* __restrict__ f2,
    float* __restrict__ corr,      // (32,162,65,65)
    int obase)
{
    int bx = blockIdx.x;
    int dy = bx >> 1, xt = bx & 1;
    int y  = blockIdx.y;
    int n  = blockIdx.z;
    int xs = xt ? 33 : 0;
    int nx = xt ? 32 : 33;
    __shared__ __align__(16) float s1[33 * 132];
    __shared__ __align__(16) float s2[41 * 132];
    int tid = threadIdx.x;
    const float4* g1 = (const float4*)(f1 + ((size_t)(n * EG + y) * EG + xs) * 128);
    float4* s1v = (float4*)s1;
    for (int e = tid; e < nx * 32; e += 128) {
        int xl = e >> 5, c4 = e & 31;
        s1v[xl * 33 + c4] = g1[xl * 32 + c4];
    }
    int y2 = y + dy - 4;
    bool yok = (y2 >= 0 && y2 < EG);
    const float4* g2 = (const float4*)(f2 + (yok ? ((size_t)(n * EG + y2) * EG) * 128 : 0));
    float4* s2v = (float4*)s2;
    for (int e = tid; e < 41 * 32; e += 128) {
        int xl = e >> 5, c4 = e & 31;
        int xg = xs - 4 + xl;
        float4 v = make_float4(0.f, 0.f, 0.f, 0.f);
        if (yok && xg >= 0 && xg < EG) v = g2[xg * 32 + c4];
        s2v[xl * 33 + c4] = v;
    }
    __syncthreads();
    int nact = nx * 3;
    if (tid < nact) {
        int q, xl;
        if (xt) { q = tid >> 5; xl = tid & 31; }
        else    { q = tid / 33; xl = tid - q * 33; }
        int dx0 = q * 3;
        float4 a0 = make_float4(0,0,0,0), a1 = a0, a2 = a0;
        const float4* r1 = (const float4*)s1 + xl * 33;
        const float4* r2 = (const float4*)s2 + (xl + dx0) * 33;
#pragma unroll 8
        for (int i = 0; i < 32; ++i) {
            float4 a = r1[i];
            float4 b0 = r2[i], b1 = r2[33 + i], b2 = r2[66 + i];
            a0.x += a.x * b0.x; a0.y += a.y * b0.y; a0.z += a.z * b0.z; a0.w += a.w * b0.w;
            a1.x += a.x * b1.x; a1.y += a.y * b1.y; a1.z += a.z * b1.z; a1.w += a.w * b1.w;
            a2.x += a.x * b2.x; a2.y += a.y * b2.y; a2.z += a.z * b2.z; a2.w += a.w * b2.w;
        }
        float s[3];
        s[0] = (a0.x + a0.y + a0.z + a0.w) * (1.0f / 128.0f);
        s[1] = (a1.x + a1.y + a1.z + a1.w) * (1.0f / 128.0f);
        s[2] = (a2.x + a2.y + a2.z + a2.w) * (1.0f / 128.0f);
#pragma unroll
        for (int m = 0; m < 3; ++m) {
            int o = obase + dy * 9 + dx0 + m;
            corr[(size_t)(n * 162 + o) * EGP + y * EG + xs + xl] = s[m];
        }
    }
}

// ---------------- conv1 (fused up2x 65->130), both branches -----------------
// grid (65, 32) : yp, n. block 128 (104 active: og(4) x xg(26), 5 x per xg,
// 2 y rows per block). ci chunks of 9 (18 chunks).
__global__ __launch_bounds__(128) void k_conv1(
    const float* __restrict__ corr,   // (32,162,65,65)
    const float* __restrict__ w_phi,  // (8,162,3,3)
    const float* __restrict__ w_vor,
    const float* __restrict__ g_phi, const float* __restrict__ b_phi,
    const float* __restrict__ g_vor, const float* __restrict__ b_vor,
    float* __restrict__ h1)           // (2,32,8,130,130)
{
    int yp = blockIdx.x;
    int n  = blockIdx.y;
    int y0 = yp * 2;
    __shared__ float craw[4 * 9 * 65];   // 2340
    __shared__ float upc [4 * 9 * 132];  // 4752
    __shared__ float wch [16 * 81];      // 1296
    int tid = threadIdx.x;
    int ylo = y0 - 1; if (ylo < 0) ylo = 0;
    int R0 = (int)((float)(ylo * 64) / 129.0f);
    int og = tid / 26, xg = tid - og * 26;
    int x0 = xg * 5;
    float acc[4][2][5] = {};
    for (int cc = 0; cc < 18; ++cc) {
        int cb = cc * 9;
        __syncthreads();
        for (int e = tid; e < 2340; e += 128) {
            int r = e / 585, rem = e - r * 585, ci = rem / 65, xx = rem - ci * 65;
            int R = R0 + r; if (R > 64) R = 64;
            craw[e] = corr[(size_t)(n * 162 + cb + ci) * EGP + R * EG + xx];
        }
        for (int e = tid; e < 1296; e += 128) {
            int t2o = e / 81, rem = e - t2o * 81, ci = rem / 9, k = rem - ci * 9;
            int t2 = t2o >> 3, o = t2o & 7;
            const float* wsrc = t2 ? w_vor : w_phi;
            wch[e] = wsrc[(o * 162 + cb + ci) * 9 + k];
        }
        __syncthreads();
        for (int e = tid; e < 4752; e += 128) {
            int r = e / 1188, rem = e - r * 1188, ci = rem / 132, xx = rem - ci * 132;
            float val = 0.f;
            int yy = y0 - 1 + r;
            int xu = xx - 1;
            if (yy >= 0 && yy <= 129 && xu >= 0 && xu <= 129) {
                float cy = (float)(yy * 64) / 129.0f;
                int iy0 = (int)cy;
                float wy = cy - (float)iy0;
                int iy1 = iy0 + 1; if (iy1 > 64) iy1 = 64;
                float cx = (float)(xu * 64) / 129.0f;
                int ix0 = (int)cx;
                float wx = cx - (float)ix0;
                int ix1 = ix0 + 1; if (ix1 > 64) ix1 = 64;
                const float* c0 = &craw[((iy0 - R0) * 9 + ci) * 65];
                const float* c1 = &craw[((iy1 - R0) * 9 + ci) * 65];
                float top = c0[ix0] + wx * (c0[ix1] - c0[ix0]);
                float bot = c1[ix0] + wx * (c1[ix1] - c1[ix0]);
                val = top + wy * (bot - top);
            }
            upc[e] = val;
        }
        __syncthreads();
        if (tid < 104) {
            for (int ci = 0; ci < 9; ++ci) {
                float u[4][7];
#pragma unroll
                for (int r = 0; r < 4; ++r)
#pragma unroll
                    for (int m = 0; m < 7; ++m)
                        u[r][m] = upc[(r * 9 + ci) * 132 + x0 + m];
#pragma unroll
                for (int o4 = 0; o4 < 4; ++o4) {
                    const float* wp = &wch[(og * 4 + o4) * 81 + ci * 9];
#pragma unroll
                    for (int ky = 0; ky < 3; ++ky)
#pragma unroll
                        for (int kx = 0; kx < 3; ++kx) {
                            float w = wp[ky * 3 + kx];
#pragma unroll
                            for (int yi = 0; yi < 2; ++yi)
#pragma unroll
                                for (int xi = 0; xi < 5; ++xi)
                                    acc[o4][yi][xi] += w * u[ky + yi][xi + kx];
                        }
                }
            }
        }
    }
    if (tid < 104) {
        const float bnsc = 1.0f / sqrtf(1.0f + 1e-5f);
#pragma unroll
        for (int o4 = 0; o4 < 4; ++o4) {
            int t2o = og * 4 + o4, t2 = t2o >> 3, o = t2o & 7;
            float gsc = (t2 ? g_vor[o] : g_phi[o]) * bnsc;
            float bia = (t2 ? b_vor[o] : b_phi[o]);
            size_t pb = (size_t)((t2 * 32 + n) * 8 + o) * 16900;
#pragma unroll
            for (int yi = 0; yi < 2; ++yi)
#pragma unroll
                for (int xi = 0; xi < 5; ++xi) {
                    float v = acc[o4][yi][xi] * gsc + bia;
                    h1[pb + (size_t)(y0 + yi) * 130 + (x0 + xi)] = fmaxf(v, 0.f);
                }
        }
    }
}

// ---------------- conv2 (fused up2x 130->260) + 1x1 head + helm -------------
// grid (260, 32), block 256.
__global__ __launch_bounds__(256) void k_conv2(
    const float* __restrict__ h1,
    const float* __restrict__ w_phi2, const float* __restrict__ w_vor2,
    const float* __restrict__ g_phi2, const float* __restrict__ b_phi2,
    const float* __restrict__ g_vor2, const float* __restrict__ b_vor2,
    const float* __restrict__ ow_phi, const float* __restrict__ ob_phi,
    const float* __restrict__ ow_vor, const float* __restrict__ ob_vor,
    const float* __restrict__ phi_weight, const float* __restrict__ vort_weight,
    float* __restrict__ helm)         // (32,2,260,260)
{
    int y = blockIdx.x, n = blockIdx.y;
    __shared__ float hraw[8320];   // [t2][j4][ci8][130]
    __shared__ float wch[1152];    // [t2][o][ci][9]
    __shared__ float bns[16], bnb[16], owv[16], obv[2], wm[2];
    int tid = threadIdx.x;
    int ylo = y - 1; if (ylo < 0) ylo = 0;
    int R0 = (int)((float)(ylo * 129) / 259.0f);
    for (int e = tid; e < 8320; e += 256) {
        int t2 = e / 4160, rem = e - t2 * 4160;
        int j = rem / 1040, rem2 = rem - j * 1040;
        int ci = rem2 / 130, xx = rem2 - ci * 130;
        int R = R0 + j; if (R > 129) R = 129;
        hraw[e] = h1[(size_t)((t2 * 32 + n) * 8 + ci) * 16900 + R * 130 + xx];
    }
    for (int e = tid; e < 1152; e += 256) {
        int t2 = e / 576, rem = e - t2 * 576;
        int o = rem / 72, rem2 = rem - o * 72;
        int ci = rem2 / 9, k = rem2 - ci * 9;
        wch[e] = (t2 ? w_vor2 : w_phi2)[(o * 8 + ci) * 9 + k];
    }
    if (tid < 16) {
        int t2 = tid >> 3, o = tid & 7;
        bns[tid] = (t2 ? g_vor2[o] : g_phi2[o]) * (1.0f / sqrtf(1.0f + 1e-5f));
        bnb[tid] = (t2 ? b_vor2[o] : b_phi2[o]);
        owv[tid] = (t2 ? ow_vor[o] : ow_phi[o]);
    }
    if (tid == 0) {
        obv[0] = ob_phi[0]; obv[1] = ob_vor[0];
        wm[0] = phi_weight[0]; wm[1] = vort_weight[0] * 260.0f;
    }
    __syncthreads();
    for (int x = tid; x < HW; x += 256) {
        float wy[3]; int rj0[3], rj1[3]; bool vy[3];
#pragma unroll
        for (int ky = 0; ky < 3; ++ky) {
            int yy = y - 1 + ky;
            vy[ky] = (yy >= 0 && yy < HW);
            if (vy[ky]) {
                float cy = (float)(yy * 129) / 259.0f;
                int i0 = (int)cy; wy[ky] = cy - (float)i0;
                int i1 = i0 + 1; if (i1 > 129) i1 = 129;
                rj0[ky] = i0 - R0; rj1[ky] = i1 - R0;
            } else { wy[ky] = 0; rj0[ky] = 0; rj1[ky] = 0; }
        }
        float wxv[3]; int c0[3], c1[3]; bool vx[3];
#pragma unroll
        for (int kx = 0; kx < 3; ++kx) {
            int xxp = x - 1 + kx;
            vx[kx] = (xxp >= 0 && xxp < HW);
            if (vx[kx]) {
                float cx = (float)(xxp * 129) / 259.0f;
                int i0 = (int)cx; wxv[kx] = cx - (float)i0;
                int i1 = i0 + 1; if (i1 > 129) i1 = 129;
                c0[kx] = i0; c1[kx] = i1;
            } else { wxv[kx] = 0; c0[kx] = 0; c1[kx] = 0; }
        }
        float res[2];
#pragma unroll
        for (int t2 = 0; t2 < 2; ++t2) {
            float acc[8] = {0,0,0,0,0,0,0,0};
            for (int ci = 0; ci < 8; ++ci) {
#pragma unroll
                for (int ky = 0; ky < 3; ++ky) {
                    if (!vy[ky]) continue;
                    const float* r0p = &hraw[((t2 * 4 + rj0[ky]) * 8 + ci) * 130];
                    const float* r1p = &hraw[((t2 * 4 + rj1[ky]) * 8 + ci) * 130];
                    float u3[3];
#pragma unroll
                    for (int kx = 0; kx < 3; ++kx) {
                        if (vx[kx]) {
                            float tp = r0p[c0[kx]] + wxv[kx] * (r0p[c1[kx]] - r0p[c0[kx]]);
                            float bt = r1p[c0[kx]] + wxv[kx] * (r1p[c1[kx]] - r1p[c0[kx]]);
                            u3[kx] = tp + wy[ky] * (bt - tp);
                        } else u3[kx] = 0.f;
                    }
#pragma unroll
                    for (int o = 0; o < 8; ++o) {
                        const float* wp = &wch[((t2 * 8 + o) * 8 + ci) * 9 + ky * 3];
                        acc[o] += wp[0] * u3[0] + wp[1] * u3[1] + wp[2] * u3[2];
                    }
                }
            }
            float dot = 0.f;
#pragma unroll
            for (int o = 0; o < 8; ++o) {
                float hv = fmaxf(acc[o] * bns[t2 * 8 + o] + bnb[t2 * 8 + o], 0.f);
                dot += owv[t2 * 8 + o] * hv;
            }
            res[t2] = (dot + obv[t2]) * wm[t2];
        }
        helm[(size_t)(n * 2 + 0) * PIX_H + y * HW + x] = res[0];
        helm[(size_t)(n * 2 + 1) * PIX_H + y * HW + x] = res[1];
    }
}

// ---------------- velocity stencils -----------------------------------------
__device__ __forceinline__ float K0f(int a, int b) {
    if (a < 0 || a > 5 || b < 0 || b > 5) return 0.f;
    float fa = (float)a - 2.5f, fb = (float)b - 2.5f;
    float r2 = fa * fa + fb * fb;
    return -fa / (6.28318530717958647692f * r2);
}
__device__ __forceinline__ float K1f(int a, int b) {
    if (a < 0 || a > 5 || b < 0 || b > 5) return 0.f;
    float fa = (float)a - 2.5f, fb = (float)b - 2.5f;
    float r2 = fa * fa + fb * fb;
    return fb / (6.28318530717958647692f * r2);
}

__global__ __launch_bounds__(256) void k_vel(
    const float* __restrict__ helm, float* __restrict__ vel)
{
    int idx = blockIdx.x * 256 + threadIdx.x;
    if (idx >= NIMG * PIX_T) return;
    int n = idx / PIX_T, pix = idx - n * PIX_T;
    int yy = pix / HWT, xx = pix - yy * HWT;
    const float* phi = helm + (size_t)(n * 2) * PIX_H;
    const float* s   = helm + (size_t)(n * 2 + 1) * PIX_H;
    float sv[7][7];
#pragma unroll
    for (int di = 0; di < 7; ++di) {
        int i = yy + di - 3;
#pragma unroll
        for (int dj = 0; dj < 7; ++dj) {
            int j = xx + dj - 3;
            sv[di][dj] = (i >= 0 && i < 259 && j >= 0 && j < 259) ? s[i * HW + j] : 0.f;
        }
    }
    float ax = 0.5f * (phi[(yy + 1) * HW + xx + 2] - phi[(yy + 1) * HW + xx]);
#pragma unroll
    for (int a = 0; a < 6; ++a)
#pragma unroll
        for (int d = 0; d < 7; ++d) {
            float coef = K0f(a, d) + K0f(a, d - 1);
            ax += 0.5f * coef * sv[a + 1][d];
        }
    float ay = 0.5f * (phi[(yy + 2) * HW + xx + 1] - phi[yy * HW + xx + 1]);
#pragma unroll
    for (int d = 0; d < 7; ++d)
#pragma unroll
        for (int b = 0; b < 6; ++b) {
            float coef = K1f(d, b) + K1f(d - 1, b);
            ay += 0.5f * coef * sv[d][b + 1];
        }
    vel[(size_t)(n * 2) * PIX_T + pix]     = ax;
    vel[(size_t)(n * 2 + 1) * PIX_T + pix] = ay;
}

// ---------------- bilinear warp ---------------------------------------------
__device__ __forceinline__ float bsample(const float* __restrict__ plane,
                                         float px, float py) {
    px = fminf(fmaxf(px, 0.f), 257.f);
    py = fminf(fmaxf(py, 0.f), 257.f);
    float fx = floorf(px), fy = floorf(py);
    int x0 = (int)fx, y0 = (int)fy;
    float wx = px - fx, wy = py - fy;
    int x1 = x0 + 1; if (x1 > 257) x1 = 257;
    int y1 = y0 + 1; if (y1 > 257) y1 = 257;
    const float* r0 = plane + y0 * HWT;
    const float* r1 = plane + y1 * HWT;
    float v00 = r0[x0], v01 = r0[x1], v10 = r1[x0], v11 = r1[x1];
    float tp = v00 + wx * (v01 - v00);
    float bt = v10 + wx * (v11 - v10);
    return tp + wy * (bt - tp);
}

__global__ __launch_bounds__(256) void k_warp(
    const float* __restrict__ src,
    const float* __restrict__ vel,
    float sign,
    const float* __restrict__ tex,
    int mode,                      // 0: sample->out ; 1: out = 1.5*tex - 0.5*sample
    float* __restrict__ out)
{
    int idx = blockIdx.x * 256 + threadIdx.x;
    if (idx >= NIMG * 8 * PIX_T) return;
    int plane_i = idx / PIX_T;
    int pix = idx - plane_i * PIX_T;
    int n = plane_i >> 3;
    int y = pix / HWT, x = pix - y * HWT;
    float vx = vel[(size_t)(n * 2) * PIX_T + pix];
    float vy = vel[(size_t)(n * 2 + 1) * PIX_T + pix];
    const float* plane = src + (size_t)plane_i * PIX_T;
    float v = bsample(plane, (float)x - sign * vx, (float)y - sign * vy);
    if (mode) v = 1.5f * tex[idx] - 0.5f * v;
    out[idx] = v;
}

// ---------------- LayerNorm + MLP residual (in-place on d_out) --------------
// grid (258, 4), block 256.
__global__ __launch_bounds__(256, 2) void k_lnmlp(
    float* __restrict__ out,
    const float* __restrict__ lng, const float* __restrict__ lnb,
    const float* __restrict__ w1, const float* __restrict__ b1,
    const float* __restrict__ w2, const float* __restrict__ b2)
{
    int yy = blockIdx.x, b = blockIdx.y;
    __shared__ __align__(16) float sw1[4096];
    __shared__ __align__(16) float sw2t[4096];  // transposed: [j][j2]
    __shared__ float sb1[64], sb2[64], sg[64], sbt[64];
    int tid = threadIdx.x;
    for (int e = tid; e < 4096; e += 256) {
        sw1[e] = w1[e];
        sw2t[(e & 63) * 64 + (e >> 6)] = w2[e];
    }
    if (tid < 64) { sb1[tid] = b1[tid]; sb2[tid] = b2[tid]; sg[tid] = lng[tid]; sbt[tid] = lnb[tid]; }
    __syncthreads();
    float* base = out + (size_t)b * 64 * PIX_T + (size_t)yy * HWT;
    for (int x = tid; x < HWT; x += 256) {
        float sum = 0.f, sumsq = 0.f;
        for (int k = 0; k < 64; ++k) {
            float v = base[(size_t)k * PIX_T + x];
            sum += v; sumsq += v * v;
        }
        float mu = sum * (1.0f / 64.0f);
        float var = sumsq * (1.0f / 64.0f) - mu * mu;
        float inv = 1.0f / sqrtf(var + 1e-5f);
        float xn[64];
#pragma unroll
        for (int k = 0; k < 64; ++k) {
            float v = base[(size_t)k * PIX_T + x];
            xn[k] = (v - mu) * inv * sg[k] + sbt[k];
        }
        float acc2[64];
#pragma unroll
        for (int j2 = 0; j2 < 64; ++j2) acc2[j2] = 0.f;
        for (int j = 0; j < 64; ++j) {
            float t = sb1[j];
            const float4* wrow = (const float4*)&sw1[j * 64];
#pragma unroll
            for (int k4 = 0; k4 < 16; ++k4) {
                float4 w = wrow[k4];
                t += xn[4 * k4] * w.x + xn[4 * k4 + 1] * w.y
                   + xn[4 * k4 + 2] * w.z + xn[4 * k4 + 3] * w.w;
            }
            float hj = 0.5f * t * (1.0f + erff(t * 0.70710678118654752f));
            const float4* w2row = (const float4*)&sw2t[j * 64];
#pragma unroll
            for (int q = 0; q < 16; ++q) {
                float4 w = w2row[q];
                acc2[4 * q]     += hj * w.x;
                acc2[4 * q + 1] += hj * w.y;
                acc2[4 * q + 2] += hj * w.z;
                acc2[4 * q + 3] += hj * w.w;
            }
        }
#pragma unroll
        for (int j2 = 0; j2 < 64; ++j2)
            base[(size_t)j2 * PIX_T + x] += sb2[j2] + acc2[j2];
    }
}

// ---------------------------------------------------------------------------
extern "C" void kernel_launch(void* const* d_in, const int* in_sizes, int n_in,
                              void* d_out, int out_size, void* d_ws, size_t ws_size,
                              hipStream_t stream) {
    const float* prev       = (const float*)d_in[0];
    const float* next       = (const float*)d_in[1];
    const float* texture    = (const float*)d_in[2];
    const float* mask       = (const float*)d_in[3];
    const float* boundary   = (const float*)d_in[4];
    const float* enc_w      = (const float*)d_in[5];
    const float* enc_b      = (const float*)d_in[6];
    const float* phi_w1     = (const float*)d_in[7];
    const float* phi_g1     = (const float*)d_in[8];
    const float* phi_b1     = (const float*)d_in[9];
    const float* phi_w2     = (const float*)d_in[10];
    const float* phi_g2     = (const float*)d_in[11];
    const float* phi_b2     = (const float*)d_in[12];
    const float* phi_ow     = (const float*)d_in[13];
    const float* phi_ob     = (const float*)d_in[14];
    const float* vor_w1     = (const float*)d_in[15];
    const float* vor_g1     = (const float*)d_in[16];
    const float* vor_b1     = (const float*)d_in[17];
    const float* vor_w2     = (const float*)d_in[18];
    const float* vor_g2     = (const float*)d_in[19];
    const float* vor_b2     = (const float*)d_in[20];
    const float* vor_ow     = (const float*)d_in[21];
    const float* vor_ob     = (const float*)d_in[22];
    const float* phi_weight = (const float*)d_in[23];
    const float* vor_weight = (const float*)d_in[24];
    const float* ln_g       = (const float*)d_in[25];
    const float* ln_b       = (const float*)d_in[26];
    const float* fc1_w      = (const float*)d_in[27];
    const float* fc1_b      = (const float*)d_in[28];
    const float* fc2_w      = (const float*)d_in[29];
    const float* fc2_b      = (const float*)d_in[30];

    float* ws = (float*)d_ws;
    // region plan (floats). peak 56,529,984 floats = 226.1 MB
    float* F_NM = ws + 0;          // 17,305,600
    float* F_A  = ws + 17305600;   // 17,305,600
    float* CORR = ws + 34611200;   // 21,902,400
    float* WT   = ws + 56513600;   // 16,384
    float* H1   = ws + 0;          // 8,652,800  (reuses F_NM after corr)
    float* HELM = ws + 17305600;   // 4,326,400  (reuses F_A)
    float* VEL  = ws + 21632000;   // 4,260,096  (within old F_A region)
    float* F1B  = ws + 34611200;   // 17,040,384 (reuses CORR)
    float* F2B  = ws + 0;          // 17,040,384 (reuses H1)
    float* OUT  = (float*)d_out;

    k_wt<<<dim3(64), dim3(256), 0, stream>>>(enc_w, WT);

    dim3 encg(5, 65, 32);
    k_enc<<<encg, dim3(128), 0, stream>>>(next, mask, WT, enc_b, F_NM);
    k_enc<<<encg, dim3(128), 0, stream>>>(prev, mask, WT, enc_b, F_A);

    dim3 corrg(18, 65, 32);
    k_corr<<<corrg, dim3(128), 0, stream>>>(F_A, F_NM, CORR, 0);
    k_enc<<<encg, dim3(128), 0, stream>>>(prev, boundary, WT, enc_b, F_A);
    k_corr<<<corrg, dim3(128), 0, stream>>>(F_A, F_NM, CORR, 81);

    k_conv1<<<dim3(65, 32), dim3(128), 0, stream>>>(
        CORR, phi_w1, vor_w1, phi_g1, phi_b1, vor_g1, vor_b1, H1);

    k_conv2<<<dim3(260, 32), dim3(256), 0, stream>>>(
        H1, phi_w2, vor_w2, phi_g2, phi_b2, vor_g2, vor_b2,
        phi_ow, phi_ob, vor_ow, vor_ob, phi_weight, vor_weight, HELM);

    int nv = NIMG * PIX_T;
    k_vel<<<dim3((nv + 255) / 256), dim3(256), 0, stream>>>(HELM, VEL);

    int nw = NIMG * 8 * PIX_T;
    int wb = (nw + 255) / 256;
    k_warp<<<dim3(wb), dim3(256), 0, stream>>>(texture, VEL,  1.0f, texture, 0, F1B);
    k_warp<<<dim3(wb), dim3(256), 0, stream>>>(F1B,     VEL, -1.0f, texture, 1, F2B);
    k_warp<<<dim3(wb), dim3(256), 0, stream>>>(F2B,     VEL,  1.0f, texture, 0, OUT);

    k_lnmlp<<<dim3(258, 4), dim3(256), 0, stream>>>(
        OUT, ln_g, ln_b, fc1_w, fc1_b, fc2_w, fc2_b);
}

// Round 2
// 3459.763 us; speedup vs baseline: 1.0066x; 1.0066x over previous
//
#include <hip/hip_runtime.h>
#include <math.h>

// ---------------------------------------------------------------------------
// Model_31009663877809: fluid advection net forward, f32.
// Round 1: k_conv1 up2x interpolation via precomputed per-block LDS tables
//          (removes ~356M f32 divisions that dominated the kernel).
// ---------------------------------------------------------------------------

#define NIMG 32          // B*G
#define HW 260
#define HWT 258
#define EG 65            // enc grid
#define EGP (EG*EG)      // 4225
#define DENC 128
#define PIX_T (HWT*HWT)  // 66564
#define PIX_H (HW*HW)    // 67600

// ---------------- enc_w transpose: wt[i*128+d] = w[d*128+i] -----------------
__global__ void k_wt(const float* __restrict__ w, float* __restrict__ wt) {
    int e = blockIdx.x * 256 + threadIdx.x;
    if (e < 128 * 128) {
        int d = e >> 7, i = e & 127;
        wt[i * 128 + d] = w[e];
    }
}

// ---------------- encoder: conv 4x4 stride 4, NHWC output -------------------
// grid (5, 65, 32), block 128. Each block: 16 consecutive xo for one (n, yo).
__global__ __launch_bounds__(128) void k_enc(
    const float* __restrict__ src,   // (4,64,260,260)
    const float* __restrict__ mul,   // (4,260,260)
    const float* __restrict__ wt,    // (128i,128d) transposed
    const float* __restrict__ bias,  // (128)
    float* __restrict__ out)         // (32,65,65,128) NHWC
{
    int xt = blockIdx.x;             // 0..4
    int yo = blockIdx.y;             // 0..64
    int n  = blockIdx.z;             // 0..31
    int bi = n >> 3, g = n & 7;
    int xo0 = xt * 16;
    __shared__ __align__(16) float patch[2048];  // [c*4+r][64 cols]
    int tid = threadIdx.x;
    const float* sbase = src + (size_t)(bi * 64 + g * 8) * PIX_H;
    const float* mbase = mul + (size_t)bi * PIX_H;
    int row0 = yo * 4, col0 = xo0 * 4;
    for (int e = tid; e < 2048; e += 128) {
        int c = e >> 8, r = (e >> 6) & 3, col = e & 63;
        int gc = col0 + col;
        float v = 0.f;
        if (gc < HW) {
            int off = (row0 + r) * HW + gc;
            v = sbase[(size_t)c * PIX_H + off] * mbase[off];
        }
        patch[e] = v;
    }
    __syncthreads();
    int d = tid;
    float acc[16];
    float bv = bias[d];
#pragma unroll
    for (int p = 0; p < 16; ++p) acc[p] = bv;
    const float4* p4 = (const float4*)patch;
    for (int j = 0; j < 32; ++j) {   // j = c*4 + ky
        float w0 = wt[(j * 4 + 0) * 128 + d];
        float w1 = wt[(j * 4 + 1) * 128 + d];
        float w2 = wt[(j * 4 + 2) * 128 + d];
        float w3 = wt[(j * 4 + 3) * 128 + d];
#pragma unroll
        for (int p = 0; p < 16; ++p) {
            float4 v = p4[j * 16 + p];
            acc[p] += w0 * v.x + w1 * v.y + w2 * v.z + w3 * v.w;
        }
    }
    size_t ob = ((size_t)(n * EG + yo) * EG + xo0) * 128 + d;
#pragma unroll
    for (int p = 0; p < 16; ++p)
        if (xo0 + p < EG) out[ob + (size_t)p * 128] = acc[p];
}

// ---------------- correlation ------------------------------------------------
// grid (18, 65, 32): bx = dy*2+xt. block 128. LDS rows padded to 132 floats.
__global__ __launch_bounds__(128) void k_corr(
    const float* __restrict__ f1,  // (32,65,65,128)
    const float* __restrict__ f2,
    float* __restrict__ corr,      // (32,162,65,65)
    int obase)
{
    int bx = blockIdx.x;
    int dy = bx >> 1, xt = bx & 1;
    int y  = blockIdx.y;
    int n  = blockIdx.z;
    int xs = xt ? 33 : 0;
    int nx = xt ? 32 : 33;
    __shared__ __align__(16) float s1[33 * 132];
    __shared__ __align__(16) float s2[41 * 132];
    int tid = threadIdx.x;
    const float4* g1 = (const float4*)(f1 + ((size_t)(n * EG + y) * EG + xs) * 128);
    float4* s1v = (float4*)s1;
    for (int e = tid; e < nx * 32; e += 128) {
        int xl = e >> 5, c4 = e & 31;
        s1v[xl * 33 + c4] = g1[xl * 32 + c4];
    }
    int y2 = y + dy - 4;
    bool yok = (y2 >= 0 && y2 < EG);
    const float4* g2 = (const float4*)(f2 + (yok ? ((size_t)(n * EG + y2) * EG) * 128 : 0));
    float4* s2v = (float4*)s2;
    for (int e = tid; e < 41 * 32; e += 128) {
        int xl = e >> 5, c4 = e & 31;
        int xg = xs - 4 + xl;
        float4 v = make_float4(0.f, 0.f, 0.f, 0.f);
        if (yok && xg >= 0 && xg < EG) v = g2[xg * 32 + c4];
        s2v[xl * 33 + c4] = v;
    }
    __syncthreads();
    int nact = nx * 3;
    if (tid < nact) {
        int q, xl;
        if (xt) { q = tid >> 5; xl = tid & 31; }
        else    { q = tid / 33; xl = tid - q * 33; }
        int dx0 = q * 3;
        float4 a0 = make_float4(0,0,0,0), a1 = a0, a2 = a0;
        const float4* r1 = (const float4*)s1 + xl * 33;
        const float4* r2 = (const float4*)s2 + (xl + dx0) * 33;
#pragma unroll 8
        for (int i = 0; i < 32; ++i) {
            float4 a = r1[i];
            float4 b0 = r2[i], b1 = r2[33 + i], b2 = r2[66 + i];
            a0.x += a.x * b0.x; a0.y += a.y * b0.y; a0.z += a.z * b0.z; a0.w += a.w * b0.w;
            a1.x += a.x * b1.x; a1.y += a.y * b1.y; a1.z += a.z * b1.z; a1.w += a.w * b1.w;
            a2.x += a.x * b2.x; a2.y += a.y * b2.y; a2.z += a.z * b2.z; a2.w += a.w * b2.w;
        }
        float s[3];
        s[0] = (a0.x + a0.y + a0.z + a0.w) * (1.0f / 128.0f);
        s[1] = (a1.x + a1.y + a1.z + a1.w) * (1.0f / 128.0f);
        s[2] = (a2.x + a2.y + a2.z + a2.w) * (1.0f / 128.0f);
#pragma unroll
        for (int m = 0; m < 3; ++m) {
            int o = obase + dy * 9 + dx0 + m;
            corr[(size_t)(n * 162 + o) * EGP + y * EG + xs + xl] = s[m];
        }
    }
}

// ---------------- conv1 (fused up2x 65->130), both branches -----------------
// grid (65, 32) : yp, n. block 128 (104 active: og(4) x xg(26), 5 x per xg,
// 2 y rows per block). ci chunks of 9 (18 chunks).
// up2x interpolation indices/weights precomputed once per block in LDS.
__global__ __launch_bounds__(128) void k_conv1(
    const float* __restrict__ corr,   // (32,162,65,65)
    const float* __restrict__ w_phi,  // (8,162,3,3)
    const float* __restrict__ w_vor,
    const float* __restrict__ g_phi, const float* __restrict__ b_phi,
    const float* __restrict__ g_vor, const float* __restrict__ b_vor,
    float* __restrict__ h1)           // (2,32,8,130,130)
{
    int yp = blockIdx.x;
    int n  = blockIdx.y;
    int y0 = yp * 2;
    __shared__ float craw[4 * 9 * 65];   // 2340
    __shared__ float upc [4 * 9 * 132];  // 4752
    __shared__ float wch [16 * 81];      // 1296
    __shared__ float s_xw[132];
    __shared__ int   s_xi0[132];
    __shared__ int   s_xi1[132];
    __shared__ float s_yw[4];
    __shared__ int   s_yj0[4];
    __shared__ int   s_yj1[4];
    __shared__ int   s_yv[4];
    int tid = threadIdx.x;
    int ylo = y0 - 1; if (ylo < 0) ylo = 0;
    int R0 = (int)((float)(ylo * 64) / 129.0f);
    // interpolation tables (same f32 arithmetic as reference; computed once)
    if (tid < 132) {
        int xu = tid - 1;
        if (xu >= 0 && xu <= 129) {
            float cx = (float)(xu * 64) / 129.0f;
            int i0 = (int)cx;
            int i1 = i0 + 1; if (i1 > 64) i1 = 64;
            s_xw[tid] = cx - (float)i0;
            s_xi0[tid] = i0;
            s_xi1[tid] = i1;
        } else { s_xi0[tid] = -1; s_xi1[tid] = 0; s_xw[tid] = 0.f; }
    }
    if (tid >= 132 && tid < 136) {
        int r = tid - 132;
        int yy = y0 - 1 + r;
        if (yy >= 0 && yy <= 129) {
            float cy = (float)(yy * 64) / 129.0f;
            int i0 = (int)cy;
            int i1 = i0 + 1; if (i1 > 64) i1 = 64;
            s_yw[r] = cy - (float)i0;
            s_yj0[r] = i0 - R0;
            s_yj1[r] = i1 - R0;
            s_yv[r] = 1;
        } else { s_yw[r] = 0.f; s_yj0[r] = 0; s_yj1[r] = 0; s_yv[r] = 0; }
    }
    int og = tid / 26, xg = tid - og * 26;
    int x0 = xg * 5;
    float acc[4][2][5] = {};
    for (int cc = 0; cc < 18; ++cc) {
        int cb = cc * 9;
        __syncthreads();
        for (int e = tid; e < 2340; e += 128) {
            int r = e / 585, rem = e - r * 585, ci = rem / 65, xx = rem - ci * 65;
            int R = R0 + r; if (R > 64) R = 64;
            craw[e] = corr[(size_t)(n * 162 + cb + ci) * EGP + R * EG + xx];
        }
        for (int e = tid; e < 1296; e += 128) {
            int t2o = e / 81, rem = e - t2o * 81, ci = rem / 9, k = rem - ci * 9;
            int t2 = t2o >> 3, o = t2o & 7;
            const float* wsrc = t2 ? w_vor : w_phi;
            wch[e] = wsrc[(o * 162 + cb + ci) * 9 + k];
        }
        __syncthreads();
        for (int e = tid; e < 4752; e += 128) {
            int r = e / 1188, rem = e - r * 1188, ci = rem / 132, xx = rem - ci * 132;
            float val = 0.f;
            int xi0 = s_xi0[xx];
            if (s_yv[r] && xi0 >= 0) {
                int xi1 = s_xi1[xx];
                float wx = s_xw[xx];
                const float* c0 = &craw[(s_yj0[r] * 9 + ci) * 65];
                const float* c1 = &craw[(s_yj1[r] * 9 + ci) * 65];
                float a0 = c0[xi0], a1 = c0[xi1];
                float b0 = c1[xi0], b1 = c1[xi1];
                float tp = a0 + wx * (a1 - a0);
                float bt = b0 + wx * (b1 - b0);
                val = tp + s_yw[r] * (bt - tp);
            }
            upc[e] = val;
        }
        __syncthreads();
        if (tid < 104) {
            for (int ci = 0; ci < 9; ++ci) {
                float u[4][7];
#pragma unroll
                for (int r = 0; r < 4; ++r)
#pragma unroll
                    for (int m = 0; m < 7; ++m)
                        u[r][m] = upc[(r * 9 + ci) * 132 + x0 + m];
#pragma unroll
                for (int o4 = 0; o4 < 4; ++o4) {
                    const float* wp = &wch[(og * 4 + o4) * 81 + ci * 9];
#pragma unroll
                    for (int ky = 0; ky < 3; ++ky)
#pragma unroll
                        for (int kx = 0; kx < 3; ++kx) {
                            float w = wp[ky * 3 + kx];
#pragma unroll
                            for (int yi = 0; yi < 2; ++yi)
#pragma unroll
                                for (int xi = 0; xi < 5; ++xi)
                                    acc[o4][yi][xi] += w * u[ky + yi][xi + kx];
                        }
                }
            }
        }
    }
    if (tid < 104) {
        const float bnsc = 1.0f / sqrtf(1.0f + 1e-5f);
#pragma unroll
        for (int o4 = 0; o4 < 4; ++o4) {
            int t2o = og * 4 + o4, t2 = t2o >> 3, o = t2o & 7;
            float gsc = (t2 ? g_vor[o] : g_phi[o]) * bnsc;
            float bia = (t2 ? b_vor[o] : b_phi[o]);
            size_t pb = (size_t)((t2 * 32 + n) * 8 + o) * 16900;
#pragma unroll
            for (int yi = 0; yi < 2; ++yi)
#pragma unroll
                for (int xi = 0; xi < 5; ++xi) {
                    float v = acc[o4][yi][xi] * gsc + bia;
                    h1[pb + (size_t)(y0 + yi) * 130 + (x0 + xi)] = fmaxf(v, 0.f);
                }
        }
    }
}

// ---------------- conv2 (fused up2x 130->260) + 1x1 head + helm -------------
// grid (260, 32), block 256.
__global__ __launch_bounds__(256) void k_conv2(
    const float* __restrict__ h1,
    const float* __restrict__ w_phi2, const float* __restrict__ w_vor2,
    const float* __restrict__ g_phi2, const float* __restrict__ b_phi2,
    const float* __restrict__ g_vor2, const float* __restrict__ b_vor2,
    const float* __restrict__ ow_phi, const float* __restrict__ ob_phi,
    const float* __restrict__ ow_vor, const float* __restrict__ ob_vor,
    const float* __restrict__ phi_weight, const float* __restrict__ vort_weight,
    float* __restrict__ helm)         // (32,2,260,260)
{
    int y = blockIdx.x, n = blockIdx.y;
    __shared__ float hraw[8320];   // [t2][j4][ci8][130]
    __shared__ float wch[1152];    // [t2][o][ci][9]
    __shared__ float bns[16], bnb[16], owv[16], obv[2], wm[2];
    int tid = threadIdx.x;
    int ylo = y - 1; if (ylo < 0) ylo = 0;
    int R0 = (int)((float)(ylo * 129) / 259.0f);
    for (int e = tid; e < 8320; e += 256) {
        int t2 = e / 4160, rem = e - t2 * 4160;
        int j = rem / 1040, rem2 = rem - j * 1040;
        int ci = rem2 / 130, xx = rem2 - ci * 130;
        int R = R0 + j; if (R > 129) R = 129;
        hraw[e] = h1[(size_t)((t2 * 32 + n) * 8 + ci) * 16900 + R * 130 + xx];
    }
    for (int e = tid; e < 1152; e += 256) {
        int t2 = e / 576, rem = e - t2 * 576;
        int o = rem / 72, rem2 = rem - o * 72;
        int ci = rem2 / 9, k = rem2 - ci * 9;
        wch[e] = (t2 ? w_vor2 : w_phi2)[(o * 8 + ci) * 9 + k];
    }
    if (tid < 16) {
        int t2 = tid >> 3, o = tid & 7;
        bns[tid] = (t2 ? g_vor2[o] : g_phi2[o]) * (1.0f / sqrtf(1.0f + 1e-5f));
        bnb[tid] = (t2 ? b_vor2[o] : b_phi2[o]);
        owv[tid] = (t2 ? ow_vor[o] : ow_phi[o]);
    }
    if (tid == 0) {
        obv[0] = ob_phi[0]; obv[1] = ob_vor[0];
        wm[0] = phi_weight[0]; wm[1] = vort_weight[0] * 260.0f;
    }
    __syncthreads();
    for (int x = tid; x < HW; x += 256) {
        float wy[3]; int rj0[3], rj1[3]; bool vy[3];
#pragma unroll
        for (int ky = 0; ky < 3; ++ky) {
            int yy = y - 1 + ky;
            vy[ky] = (yy >= 0 && yy < HW);
            if (vy[ky]) {
                float cy = (float)(yy * 129) / 259.0f;
                int i0 = (int)cy; wy[ky] = cy - (float)i0;
                int i1 = i0 + 1; if (i1 > 129) i1 = 129;
                rj0[ky] = i0 - R0; rj1[ky] = i1 - R0;
            } else { wy[ky] = 0; rj0[ky] = 0; rj1[ky] = 0; }
        }
        float wxv[3]; int c0[3], c1[3]; bool vx[3];
#pragma unroll
        for (int kx = 0; kx < 3; ++kx) {
            int xxp = x - 1 + kx;
            vx[kx] = (xxp >= 0 && xxp < HW);
            if (vx[kx]) {
                float cx = (float)(xxp * 129) / 259.0f;
                int i0 = (int)cx; wxv[kx] = cx - (float)i0;
                int i1 = i0 + 1; if (i1 > 129) i1 = 129;
                c0[kx] = i0; c1[kx] = i1;
            } else { wxv[kx] = 0; c0[kx] = 0; c1[kx] = 0; }
        }
        float res[2];
#pragma unroll
        for (int t2 = 0; t2 < 2; ++t2) {
            float acc[8] = {0,0,0,0,0,0,0,0};
            for (int ci = 0; ci < 8; ++ci) {
#pragma unroll
                for (int ky = 0; ky < 3; ++ky) {
                    if (!vy[ky]) continue;
                    const float* r0p = &hraw[((t2 * 4 + rj0[ky]) * 8 + ci) * 130];
                    const float* r1p = &hraw[((t2 * 4 + rj1[ky]) * 8 + ci) * 130];
                    float u3[3];
#pragma unroll
                    for (int kx = 0; kx < 3; ++kx) {
                        if (vx[kx]) {
                            float tp = r0p[c0[kx]] + wxv[kx] * (r0p[c1[kx]] - r0p[c0[kx]]);
                            float bt = r1p[c0[kx]] + wxv[kx] * (r1p[c1[kx]] - r1p[c0[kx]]);
                            u3[kx] = tp + wy[ky] * (bt - tp);
                        } else u3[kx] = 0.f;
                    }
#pragma unroll
                    for (int o = 0; o < 8; ++o) {
                        const float* wp = &wch[((t2 * 8 + o) * 8 + ci) * 9 + ky * 3];
                        acc[o] += wp[0] * u3[0] + wp[1] * u3[1] + wp[2] * u3[2];
                    }
                }
            }
            float dot = 0.f;
#pragma unroll
            for (int o = 0; o < 8; ++o) {
                float hv = fmaxf(acc[o] * bns[t2 * 8 + o] + bnb[t2 * 8 + o], 0.f);
                dot += owv[t2 * 8 + o] * hv;
            }
            res[t2] = (dot + obv[t2]) * wm[t2];
        }
        helm[(size_t)(n * 2 + 0) * PIX_H + y * HW + x] = res[0];
        helm[(size_t)(n * 2 + 1) * PIX_H + y * HW + x] = res[1];
    }
}

// ---------------- velocity stencils -----------------------------------------
__device__ __forceinline__ float K0f(int a, int b) {
    if (a < 0 || a > 5 || b < 0 || b > 5) return 0.f;
    float fa = (float)a - 2.5f, fb = (float)b - 2.5f;
    float r2 = fa * fa + fb * fb;
    return -fa / (6.28318530717958647692f * r2);
}
__device__ __forceinline__ float K1f(int a, int b) {
    if (a < 0 || a > 5 || b < 0 || b > 5) return 0.f;
    float fa = (float)a - 2.5f, fb = (float)b - 2.5f;
    float r2 = fa * fa + fb * fb;
    return fb / (6.28318530717958647692f * r2);
}

__global__ __launch_bounds__(256) void k_vel(
    const float* __restrict__ helm, float* __restrict__ vel)
{
    int idx = blockIdx.x * 256 + threadIdx.x;
    if (idx >= NIMG * PIX_T) return;
    int n = idx / PIX_T, pix = idx - n * PIX_T;
    int yy = pix / HWT, xx = pix - yy * HWT;
    const float* phi = helm + (size_t)(n * 2) * PIX_H;
    const float* s   = helm + (size_t)(n * 2 + 1) * PIX_H;
    float sv[7][7];
#pragma unroll
    for (int di = 0; di < 7; ++di) {
        int i = yy + di - 3;
#pragma unroll
        for (int dj = 0; dj < 7; ++dj) {
            int j = xx + dj - 3;
            sv[di][dj] = (i >= 0 && i < 259 && j >= 0 && j < 259) ? s[i * HW + j] : 0.f;
        }
    }
    float ax = 0.5f * (phi[(yy + 1) * HW + xx + 2] - phi[(yy + 1) * HW + xx]);
#pragma unroll
    for (int a = 0; a < 6; ++a)
#pragma unroll
        for (int d = 0; d < 7; ++d) {
            float coef = K0f(a, d) + K0f(a, d - 1);
            ax += 0.5f * coef * sv[a + 1][d];
        }
    float ay = 0.5f * (phi[(yy + 2) * HW + xx + 1] - phi[yy * HW + xx + 1]);
#pragma unroll
    for (int d = 0; d < 7; ++d)
#pragma unroll
        for (int b = 0; b < 6; ++b) {
            float coef = K1f(d, b) + K1f(d - 1, b);
            ay += 0.5f * coef * sv[d][b + 1];
        }
    vel[(size_t)(n * 2) * PIX_T + pix]     = ax;
    vel[(size_t)(n * 2 + 1) * PIX_T + pix] = ay;
}

// ---------------- bilinear warp ---------------------------------------------
__device__ __forceinline__ float bsample(const float* __restrict__ plane,
                                         float px, float py) {
    px = fminf(fmaxf(px, 0.f), 257.f);
    py = fminf(fmaxf(py, 0.f), 257.f);
    float fx = floorf(px), fy = floorf(py);
    int x0 = (int)fx, y0 = (int)fy;
    float wx = px - fx, wy = py - fy;
    int x1 = x0 + 1; if (x1 > 257) x1 = 257;
    int y1 = y0 + 1; if (y1 > 257) y1 = 257;
    const float* r0 = plane + y0 * HWT;
    const float* r1 = plane + y1 * HWT;
    float v00 = r0[x0], v01 = r0[x1], v10 = r1[x0], v11 = r1[x1];
    float tp = v00 + wx * (v01 - v00);
    float bt = v10 + wx * (v11 - v10);
    return tp + wy * (bt - tp);
}

__global__ __launch_bounds__(256) void k_warp(
    const float* __restrict__ src,
    const float* __restrict__ vel,
    float sign,
    const float* __restrict__ tex,
    int mode,                      // 0: sample->out ; 1: out = 1.5*tex - 0.5*sample
    float* __restrict__ out)
{
    int idx = blockIdx.x * 256 + threadIdx.x;
    if (idx >= NIMG * 8 * PIX_T) return;
    int plane_i = idx / PIX_T;
    int pix = idx - plane_i * PIX_T;
    int n = plane_i >> 3;
    int y = pix / HWT, x = pix - y * HWT;
    float vx = vel[(size_t)(n * 2) * PIX_T + pix];
    float vy = vel[(size_t)(n * 2 + 1) * PIX_T + pix];
    const float* plane = src + (size_t)plane_i * PIX_T;
    float v = bsample(plane, (float)x - sign * vx, (float)y - sign * vy);
    if (mode) v = 1.5f * tex[idx] - 0.5f * v;
    out[idx] = v;
}

// ---------------- LayerNorm + MLP residual (in-place on d_out) --------------
// grid (258, 4), block 256.
__global__ __launch_bounds__(256, 2) void k_lnmlp(
    float* __restrict__ out,
    const float* __restrict__ lng, const float* __restrict__ lnb,
    const float* __restrict__ w1, const float* __restrict__ b1,
    const float* __restrict__ w2, const float* __restrict__ b2)
{
    int yy = blockIdx.x, b = blockIdx.y;
    __shared__ __align__(16) float sw1[4096];
    __shared__ __align__(16) float sw2t[4096];  // transposed: [j][j2]
    __shared__ float sb1[64], sb2[64], sg[64], sbt[64];
    int tid = threadIdx.x;
    for (int e = tid; e < 4096; e += 256) {
        sw1[e] = w1[e];
        sw2t[(e & 63) * 64 + (e >> 6)] = w2[e];
    }
    if (tid < 64) { sb1[tid] = b1[tid]; sb2[tid] = b2[tid]; sg[tid] = lng[tid]; sbt[tid] = lnb[tid]; }
    __syncthreads();
    float* base = out + (size_t)b * 64 * PIX_T + (size_t)yy * HWT;
    for (int x = tid; x < HWT; x += 256) {
        float sum = 0.f, sumsq = 0.f;
        for (int k = 0; k < 64; ++k) {
            float v = base[(size_t)k * PIX_T + x];
            sum += v; sumsq += v * v;
        }
        float mu = sum * (1.0f / 64.0f);
        float var = sumsq * (1.0f / 64.0f) - mu * mu;
        float inv = 1.0f / sqrtf(var + 1e-5f);
        float xn[64];
#pragma unroll
        for (int k = 0; k < 64; ++k) {
            float v = base[(size_t)k * PIX_T + x];
            xn[k] = (v - mu) * inv * sg[k] + sbt[k];
        }
        float acc2[64];
#pragma unroll
        for (int j2 = 0; j2 < 64; ++j2) acc2[j2] = 0.f;
        for (int j = 0; j < 64; ++j) {
            float t = sb1[j];
            const float4* wrow = (const float4*)&sw1[j * 64];
#pragma unroll
            for (int k4 = 0; k4 < 16; ++k4) {
                float4 w = wrow[k4];
                t += xn[4 * k4] * w.x + xn[4 * k4 + 1] * w.y
                   + xn[4 * k4 + 2] * w.z + xn[4 * k4 + 3] * w.w;
            }
            float hj = 0.5f * t * (1.0f + erff(t * 0.70710678118654752f));
            const float4* w2row = (const float4*)&sw2t[j * 64];
#pragma unroll
            for (int q = 0; q < 16; ++q) {
                float4 w = w2row[q];
                acc2[4 * q]     += hj * w.x;
                acc2[4 * q + 1] += hj * w.y;
                acc2[4 * q + 2] += hj * w.z;
                acc2[4 * q + 3] += hj * w.w;
            }
        }
#pragma unroll
        for (int j2 = 0; j2 < 64; ++j2)
            base[(size_t)j2 * PIX_T + x] += sb2[j2] + acc2[j2];
    }
}

// ---------------------------------------------------------------------------
extern "C" void kernel_launch(void* const* d_in, const int* in_sizes, int n_in,
                              void* d_out, int out_size, void* d_ws, size_t ws_size,
                              hipStream_t stream) {
    const float* prev       = (const float*)d_in[0];
    const float* next       = (const float*)d_in[1];
    const float* texture    = (const float*)d_in[2];
    const float* mask       = (const float*)d_in[3];
    const float* boundary   = (const float*)d_in[4];
    const float* enc_w      = (const float*)d_in[5];
    const float* enc_b      = (const float*)d_in[6];
    const float* phi_w1     = (const float*)d_in[7];
    const float* phi_g1     = (const float*)d_in[8];
    const float* phi_b1     = (const float*)d_in[9];
    const float* phi_w2     = (const float*)d_in[10];
    const float* phi_g2     = (const float*)d_in[11];
    const float* phi_b2     = (const float*)d_in[12];
    const float* phi_ow     = (const float*)d_in[13];
    const float* phi_ob     = (const float*)d_in[14];
    const float* vor_w1     = (const float*)d_in[15];
    const float* vor_g1     = (const float*)d_in[16];
    const float* vor_b1     = (const float*)d_in[17];
    const float* vor_w2     = (const float*)d_in[18];
    const float* vor_g2     = (const float*)d_in[19];
    const float* vor_b2     = (const float*)d_in[20];
    const float* vor_ow     = (const float*)d_in[21];
    const float* vor_ob     = (const float*)d_in[22];
    const float* phi_weight = (const float*)d_in[23];
    const float* vor_weight = (const float*)d_in[24];
    const float* ln_g       = (const float*)d_in[25];
    const float* ln_b       = (const float*)d_in[26];
    const float* fc1_w      = (const float*)d_in[27];
    const float* fc1_b      = (const float*)d_in[28];
    const float* fc2_w      = (const float*)d_in[29];
    const float* fc2_b      = (const float*)d_in[30];

    float* ws = (float*)d_ws;
    // region plan (floats). peak 56,529,984 floats = 226.1 MB
    float* F_NM = ws + 0;          // 17,305,600
    float* F_A  = ws + 17305600;   // 17,305,600
    float* CORR = ws + 34611200;   // 21,902,400
    float* WT   = ws + 56513600;   // 16,384
    float* H1   = ws + 0;          // 8,652,800  (reuses F_NM after corr)
    float* HELM = ws + 17305600;   // 4,326,400  (reuses F_A)
    float* VEL  = ws + 21632000;   // 4,260,096  (within old F_A region)
    float* F1B  = ws + 34611200;   // 17,040,384 (reuses CORR)
    float* F2B  = ws + 0;          // 17,040,384 (reuses H1)
    float* OUT  = (float*)d_out;

    k_wt<<<dim3(64), dim3(256), 0, stream>>>(enc_w, WT);

    dim3 encg(5, 65, 32);
    k_enc<<<encg, dim3(128), 0, stream>>>(next, mask, WT, enc_b, F_NM);
    k_enc<<<encg, dim3(128), 0, stream>>>(prev, mask, WT, enc_b, F_A);

    dim3 corrg(18, 65, 32);
    k_corr<<<corrg, dim3(128), 0, stream>>>(F_A, F_NM, CORR, 0);
    k_enc<<<encg, dim3(128), 0, stream>>>(prev, boundary, WT, enc_b, F_A);
    k_corr<<<corrg, dim3(128), 0, stream>>>(F_A, F_NM, CORR, 81);

    k_conv1<<<dim3(65, 32), dim3(128), 0, stream>>>(
        CORR, phi_w1, vor_w1, phi_g1, phi_b1, vor_g1, vor_b1, H1);

    k_conv2<<<dim3(260, 32), dim3(256), 0, stream>>>(
        H1, phi_w2, vor_w2, phi_g2, phi_b2, vor_g2, vor_b2,
        phi_ow, phi_ob, vor_ow, vor_ob, phi_weight, vor_weight, HELM);

    int nv = NIMG * PIX_T;
    k_vel<<<dim3((nv + 255) / 256), dim3(256), 0, stream>>>(HELM, VEL);

    int nw = NIMG * 8 * PIX_T;
    int wb = (nw + 255) / 256;
    k_warp<<<dim3(wb), dim3(256), 0, stream>>>(texture, VEL,  1.0f, texture, 0, F1B);
    k_warp<<<dim3(wb), dim3(256), 0, stream>>>(F1B,     VEL, -1.0f, texture, 1, F2B);
    k_warp<<<dim3(wb), dim3(256), 0, stream>>>(F2B,     VEL,  1.0f, texture, 0, OUT);

    k_lnmlp<<<dim3(258, 4), dim3(256), 0, stream>>>(
        OUT, ln_g, ln_b, fc1_w, fc1_b, fc2_w, fc2_b);
}

// Round 3
// 3074.732 us; speedup vs baseline: 1.1326x; 1.1252x over previous
//
#include <hip/hip_runtime.h>
#include <math.h>

// ---------------------------------------------------------------------------
// Model_31009663877809: fluid advection net forward, f32.
// Round 2: k_conv1 restructured for occupancy/latency:
//   - 256-thread blocks, 4 output rows x 130 cols x 16 oc per block
//   - upc interpolated directly from global corr (no craw stage; 2 barriers)
//   - LDS 24 KB -> ~6 blocks/CU (was 4 blocks x 2 waves at 35 KB)
// ---------------------------------------------------------------------------

#define NIMG 32          // B*G
#define HW 260
#define HWT 258
#define EG 65            // enc grid
#define EGP (EG*EG)      // 4225
#define DENC 128
#define PIX_T (HWT*HWT)  // 66564
#define PIX_H (HW*HW)    // 67600

// ---------------- enc_w transpose: wt[i*128+d] = w[d*128+i] -----------------
__global__ void k_wt(const float* __restrict__ w, float* __restrict__ wt) {
    int e = blockIdx.x * 256 + threadIdx.x;
    if (e < 128 * 128) {
        int d = e >> 7, i = e & 127;
        wt[i * 128 + d] = w[e];
    }
}

// ---------------- encoder: conv 4x4 stride 4, NHWC output -------------------
// grid (5, 65, 32), block 128. Each block: 16 consecutive xo for one (n, yo).
__global__ __launch_bounds__(128) void k_enc(
    const float* __restrict__ src,   // (4,64,260,260)
    const float* __restrict__ mul,   // (4,260,260)
    const float* __restrict__ wt,    // (128i,128d) transposed
    const float* __restrict__ bias,  // (128)
    float* __restrict__ out)         // (32,65,65,128) NHWC
{
    int xt = blockIdx.x;             // 0..4
    int yo = blockIdx.y;             // 0..64
    int n  = blockIdx.z;             // 0..31
    int bi = n >> 3, g = n & 7;
    int xo0 = xt * 16;
    __shared__ __align__(16) float patch[2048];  // [c*4+r][64 cols]
    int tid = threadIdx.x;
    const float* sbase = src + (size_t)(bi * 64 + g * 8) * PIX_H;
    const float* mbase = mul + (size_t)bi * PIX_H;
    int row0 = yo * 4, col0 = xo0 * 4;
    for (int e = tid; e < 2048; e += 128) {
        int c = e >> 8, r = (e >> 6) & 3, col = e & 63;
        int gc = col0 + col;
        float v = 0.f;
        if (gc < HW) {
            int off = (row0 + r) * HW + gc;
            v = sbase[(size_t)c * PIX_H + off] * mbase[off];
        }
        patch[e] = v;
    }
    __syncthreads();
    int d = tid;
    float acc[16];
    float bv = bias[d];
#pragma unroll
    for (int p = 0; p < 16; ++p) acc[p] = bv;
    const float4* p4 = (const float4*)patch;
    for (int j = 0; j < 32; ++j) {   // j = c*4 + ky
        float w0 = wt[(j * 4 + 0) * 128 + d];
        float w1 = wt[(j * 4 + 1) * 128 + d];
        float w2 = wt[(j * 4 + 2) * 128 + d];
        float w3 = wt[(j * 4 + 3) * 128 + d];
#pragma unroll
        for (int p = 0; p < 16; ++p) {
            float4 v = p4[j * 16 + p];
            acc[p] += w0 * v.x + w1 * v.y + w2 * v.z + w3 * v.w;
        }
    }
    size_t ob = ((size_t)(n * EG + yo) * EG + xo0) * 128 + d;
#pragma unroll
    for (int p = 0; p < 16; ++p)
        if (xo0 + p < EG) out[ob + (size_t)p * 128] = acc[p];
}

// ---------------- correlation ------------------------------------------------
// grid (18, 65, 32): bx = dy*2+xt. block 128. LDS rows padded to 132 floats.
__global__ __launch_bounds__(128) void k_corr(
    const float* __restrict__ f1,  // (32,65,65,128)
    const float* __restrict__ f2,
    float* __restrict__ corr,      // (32,162,65,65)
    int obase)
{
    int bx = blockIdx.x;
    int dy = bx >> 1, xt = bx & 1;
    int y  = blockIdx.y;
    int n  = blockIdx.z;
    int xs = xt ? 33 : 0;
    int nx = xt ? 32 : 33;
    __shared__ __align__(16) float s1[33 * 132];
    __shared__ __align__(16) float s2[41 * 132];
    int tid = threadIdx.x;
    const float4* g1 = (const float4*)(f1 + ((size_t)(n * EG + y) * EG + xs) * 128);
    float4* s1v = (float4*)s1;
    for (int e = tid; e < nx * 32; e += 128) {
        int xl = e >> 5, c4 = e & 31;
        s1v[xl * 33 + c4] = g1[xl * 32 + c4];
    }
    int y2 = y + dy - 4;
    bool yok = (y2 >= 0 && y2 < EG);
    const float4* g2 = (const float4*)(f2 + (yok ? ((size_t)(n * EG + y2) * EG) * 128 : 0));
    float4* s2v = (float4*)s2;
    for (int e = tid; e < 41 * 32; e += 128) {
        int xl = e >> 5, c4 = e & 31;
        int xg = xs - 4 + xl;
        float4 v = make_float4(0.f, 0.f, 0.f, 0.f);
        if (yok && xg >= 0 && xg < EG) v = g2[xg * 32 + c4];
        s2v[xl * 33 + c4] = v;
    }
    __syncthreads();
    int nact = nx * 3;
    if (tid < nact) {
        int q, xl;
        if (xt) { q = tid >> 5; xl = tid & 31; }
        else    { q = tid / 33; xl = tid - q * 33; }
        int dx0 = q * 3;
        float4 a0 = make_float4(0,0,0,0), a1 = a0, a2 = a0;
        const float4* r1 = (const float4*)s1 + xl * 33;
        const float4* r2 = (const float4*)s2 + (xl + dx0) * 33;
#pragma unroll 8
        for (int i = 0; i < 32; ++i) {
            float4 a = r1[i];
            float4 b0 = r2[i], b1 = r2[33 + i], b2 = r2[66 + i];
            a0.x += a.x * b0.x; a0.y += a.y * b0.y; a0.z += a.z * b0.z; a0.w += a.w * b0.w;
            a1.x += a.x * b1.x; a1.y += a.y * b1.y; a1.z += a.z * b1.z; a1.w += a.w * b1.w;
            a2.x += a.x * b2.x; a2.y += a.y * b2.y; a2.z += a.z * b2.z; a2.w += a.w * b2.w;
        }
        float s[3];
        s[0] = (a0.x + a0.y + a0.z + a0.w) * (1.0f / 128.0f);
        s[1] = (a1.x + a1.y + a1.z + a1.w) * (1.0f / 128.0f);
        s[2] = (a2.x + a2.y + a2.z + a2.w) * (1.0f / 128.0f);
#pragma unroll
        for (int m = 0; m < 3; ++m) {
            int o = obase + dy * 9 + dx0 + m;
            corr[(size_t)(n * 162 + o) * EGP + y * EG + xs + xl] = s[m];
        }
    }
}

// ---------------- conv1 (fused up2x 65->130), both branches -----------------
// grid (33, 32): yp, n. block 256. Each block: 4 output rows x 130 x 16 oc.
// 208 active compute threads: og(8) x xg(26); each 2 oc x 4y x 5x = 40 out.
// upc interpolated straight from global corr via per-block LDS tables.
__global__ __launch_bounds__(256) void k_conv1(
    const float* __restrict__ corr,   // (32,162,65,65)
    const float* __restrict__ w_phi,  // (8,162,3,3)
    const float* __restrict__ w_vor,
    const float* __restrict__ g_phi, const float* __restrict__ b_phi,
    const float* __restrict__ g_vor, const float* __restrict__ b_vor,
    float* __restrict__ h1)           // (2,32,8,130,130)
{
    int yp = blockIdx.x;              // 0..32
    int n  = blockIdx.y;              // 0..31
    int y0 = yp * 4;
    __shared__ float upc[6 * 6 * 132];   // [r6][ci6][132]  19008 B
    __shared__ float wch[16 * 6 * 9];    // [oc16][ci6][9]   3456 B
    __shared__ float s_xw[132];
    __shared__ int   s_xi0[132];
    __shared__ int   s_xi1[132];
    __shared__ float s_yw[6];
    __shared__ int   s_yj0[6];
    __shared__ int   s_yj1[6];
    __shared__ int   s_yv[6];
    int tid = threadIdx.x;
    // interpolation tables (same f32 arithmetic as reference; once per block)
    if (tid < 132) {
        int xu = tid - 1;
        if (xu >= 0 && xu <= 129) {
            float cx = (float)(xu * 64) / 129.0f;
            int i0 = (int)cx;
            int i1 = i0 + 1; if (i1 > 64) i1 = 64;
            s_xw[tid] = cx - (float)i0;
            s_xi0[tid] = i0;
            s_xi1[tid] = i1;
        } else { s_xi0[tid] = -1; s_xi1[tid] = 0; s_xw[tid] = 0.f; }
    }
    if (tid >= 132 && tid < 138) {
        int r = tid - 132;
        int yy = y0 - 1 + r;
        if (yy >= 0 && yy <= 129) {
            float cy = (float)(yy * 64) / 129.0f;
            int i0 = (int)cy;
            int i1 = i0 + 1; if (i1 > 64) i1 = 64;
            s_yw[r] = cy - (float)i0;
            s_yj0[r] = i0;
            s_yj1[r] = i1;
            s_yv[r] = 1;
        } else { s_yw[r] = 0.f; s_yj0[r] = 0; s_yj1[r] = 0; s_yv[r] = 0; }
    }
    int og = tid / 26, xg = tid - og * 26;
    int x0 = xg * 5;
    bool act = (og < 8);
    float acc[2][4][5] = {};
    for (int cc = 0; cc < 27; ++cc) {
        int cb = cc * 6;
        __syncthreads();
        // fill upc: bilinear interp straight from global corr
        for (int e = tid; e < 4752; e += 256) {
            int r = e / 792, rem = e - r * 792, ci = rem / 132, xx = rem - ci * 132;
            float val = 0.f;
            int xi0 = s_xi0[xx];
            if (s_yv[r] && xi0 >= 0) {
                const float* cp = corr + (size_t)(n * 162 + cb + ci) * EGP;
                int J0 = s_yj0[r] * 65, J1 = s_yj1[r] * 65;
                int xi1 = s_xi1[xx];
                float wxv = s_xw[xx];
                float a0 = __ldg(cp + J0 + xi0), a1 = __ldg(cp + J0 + xi1);
                float b0 = __ldg(cp + J1 + xi0), b1 = __ldg(cp + J1 + xi1);
                float tp = a0 + wxv * (a1 - a0);
                float bt = b0 + wxv * (b1 - b0);
                val = tp + s_yw[r] * (bt - tp);
            }
            upc[e] = val;
        }
        // weights for this ci-chunk
        for (int e = tid; e < 864; e += 256) {
            int oc = e / 54, rem = e - oc * 54, ci = rem / 9, k = rem - ci * 9;
            int t2 = oc >> 3, o = oc & 7;
            wch[e] = (t2 ? w_vor : w_phi)[(o * 162 + cb + ci) * 9 + k];
        }
        __syncthreads();
        if (act) {
            for (int ci = 0; ci < 6; ++ci) {
                float wr[2][9];
#pragma unroll
                for (int p = 0; p < 2; ++p)
#pragma unroll
                    for (int k = 0; k < 9; ++k)
                        wr[p][k] = wch[((og + 8 * p) * 6 + ci) * 9 + k];
#pragma unroll
                for (int r = 0; r < 6; ++r) {
                    float u7[7];
                    const float* up = &upc[(r * 6 + ci) * 132 + x0];
#pragma unroll
                    for (int m = 0; m < 7; ++m) u7[m] = up[m];
#pragma unroll
                    for (int ky = 0; ky < 3; ++ky) {
                        int yi = r - ky;
                        if (yi < 0 || yi > 3) continue;
#pragma unroll
                        for (int p = 0; p < 2; ++p)
#pragma unroll
                            for (int kx = 0; kx < 3; ++kx) {
                                float w = wr[p][ky * 3 + kx];
#pragma unroll
                                for (int xi = 0; xi < 5; ++xi)
                                    acc[p][yi][xi] += w * u7[xi + kx];
                            }
                    }
                }
            }
        }
    }
    if (act) {
        const float bnsc = 1.0f / sqrtf(1.0f + 1e-5f);
#pragma unroll
        for (int p = 0; p < 2; ++p) {
            float gsc = (p ? g_vor[og] : g_phi[og]) * bnsc;
            float bia = (p ? b_vor[og] : b_phi[og]);
            size_t pb = (size_t)((p * 32 + n) * 8 + og) * 16900;
#pragma unroll
            for (int yi = 0; yi < 4; ++yi) {
                int row = y0 + yi;
                if (row < 130) {
#pragma unroll
                    for (int xi = 0; xi < 5; ++xi) {
                        float v = acc[p][yi][xi] * gsc + bia;
                        h1[pb + (size_t)row * 130 + (x0 + xi)] = fmaxf(v, 0.f);
                    }
                }
            }
        }
    }
}

// ---------------- conv2 (fused up2x 130->260) + 1x1 head + helm -------------
// grid (260, 32), block 256.
__global__ __launch_bounds__(256) void k_conv2(
    const float* __restrict__ h1,
    const float* __restrict__ w_phi2, const float* __restrict__ w_vor2,
    const float* __restrict__ g_phi2, const float* __restrict__ b_phi2,
    const float* __restrict__ g_vor2, const float* __restrict__ b_vor2,
    const float* __restrict__ ow_phi, const float* __restrict__ ob_phi,
    const float* __restrict__ ow_vor, const float* __restrict__ ob_vor,
    const float* __restrict__ phi_weight, const float* __restrict__ vort_weight,
    float* __restrict__ helm)         // (32,2,260,260)
{
    int y = blockIdx.x, n = blockIdx.y;
    __shared__ float hraw[8320];   // [t2][j4][ci8][130]
    __shared__ float wch[1152];    // [t2][o][ci][9]
    __shared__ float bns[16], bnb[16], owv[16], obv[2], wm[2];
    int tid = threadIdx.x;
    int ylo = y - 1; if (ylo < 0) ylo = 0;
    int R0 = (int)((float)(ylo * 129) / 259.0f);
    for (int e = tid; e < 8320; e += 256) {
        int t2 = e / 4160, rem = e - t2 * 4160;
        int j = rem / 1040, rem2 = rem - j * 1040;
        int ci = rem2 / 130, xx = rem2 - ci * 130;
        int R = R0 + j; if (R > 129) R = 129;
        hraw[e] = h1[(size_t)((t2 * 32 + n) * 8 + ci) * 16900 + R * 130 + xx];
    }
    for (int e = tid; e < 1152; e += 256) {
        int t2 = e / 576, rem = e - t2 * 576;
        int o = rem / 72, rem2 = rem - o * 72;
        int ci = rem2 / 9, k = rem2 - ci * 9;
        wch[e] = (t2 ? w_vor2 : w_phi2)[(o * 8 + ci) * 9 + k];
    }
    if (tid < 16) {
        int t2 = tid >> 3, o = tid & 7;
        bns[tid] = (t2 ? g_vor2[o] : g_phi2[o]) * (1.0f / sqrtf(1.0f + 1e-5f));
        bnb[tid] = (t2 ? b_vor2[o] : b_phi2[o]);
        owv[tid] = (t2 ? ow_vor[o] : ow_phi[o]);
    }
    if (tid == 0) {
        obv[0] = ob_phi[0]; obv[1] = ob_vor[0];
        wm[0] = phi_weight[0]; wm[1] = vort_weight[0] * 260.0f;
    }
    __syncthreads();
    for (int x = tid; x < HW; x += 256) {
        float wy[3]; int rj0[3], rj1[3]; bool vy[3];
#pragma unroll
        for (int ky = 0; ky < 3; ++ky) {
            int yy = y - 1 + ky;
            vy[ky] = (yy >= 0 && yy < HW);
            if (vy[ky]) {
                float cy = (float)(yy * 129) / 259.0f;
                int i0 = (int)cy; wy[ky] = cy - (float)i0;
                int i1 = i0 + 1; if (i1 > 129) i1 = 129;
                rj0[ky] = i0 - R0; rj1[ky] = i1 - R0;
            } else { wy[ky] = 0; rj0[ky] = 0; rj1[ky] = 0; }
        }
        float wxv[3]; int c0[3], c1[3]; bool vx[3];
#pragma unroll
        for (int kx = 0; kx < 3; ++kx) {
            int xxp = x - 1 + kx;
            vx[kx] = (xxp >= 0 && xxp < HW);
            if (vx[kx]) {
                float cx = (float)(xxp * 129) / 259.0f;
                int i0 = (int)cx; wxv[kx] = cx - (float)i0;
                int i1 = i0 + 1; if (i1 > 129) i1 = 129;
                c0[kx] = i0; c1[kx] = i1;
            } else { wxv[kx] = 0; c0[kx] = 0; c1[kx] = 0; }
        }
        float res[2];
#pragma unroll
        for (int t2 = 0; t2 < 2; ++t2) {
            float acc[8] = {0,0,0,0,0,0,0,0};
            for (int ci = 0; ci < 8; ++ci) {
#pragma unroll
                for (int ky = 0; ky < 3; ++ky) {
                    if (!vy[ky]) continue;
                    const float* r0p = &hraw[((t2 * 4 + rj0[ky]) * 8 + ci) * 130];
                    const float* r1p = &hraw[((t2 * 4 + rj1[ky]) * 8 + ci) * 130];
                    float u3[3];
#pragma unroll
                    for (int kx = 0; kx < 3; ++kx) {
                        if (vx[kx]) {
                            float tp = r0p[c0[kx]] + wxv[kx] * (r0p[c1[kx]] - r0p[c0[kx]]);
                            float bt = r1p[c0[kx]] + wxv[kx] * (r1p[c1[kx]] - r1p[c0[kx]]);
                            u3[kx] = tp + wy[ky] * (bt - tp);
                        } else u3[kx] = 0.f;
                    }
#pragma unroll
                    for (int o = 0; o < 8; ++o) {
                        const float* wp = &wch[((t2 * 8 + o) * 8 + ci) * 9 + ky * 3];
                        acc[o] += wp[0] * u3[0] + wp[1] * u3[1] + wp[2] * u3[2];
                    }
                }
            }
            float dot = 0.f;
#pragma unroll
            for (int o = 0; o < 8; ++o) {
                float hv = fmaxf(acc[o] * bns[t2 * 8 + o] + bnb[t2 * 8 + o], 0.f);
                dot += owv[t2 * 8 + o] * hv;
            }
            res[t2] = (dot + obv[t2]) * wm[t2];
        }
        helm[(size_t)(n * 2 + 0) * PIX_H + y * HW + x] = res[0];
        helm[(size_t)(n * 2 + 1) * PIX_H + y * HW + x] = res[1];
    }
}

// ---------------- velocity stencils -----------------------------------------
__device__ __forceinline__ float K0f(int a, int b) {
    if (a < 0 || a > 5 || b < 0 || b > 5) return 0.f;
    float fa = (float)a - 2.5f, fb = (float)b - 2.5f;
    float r2 = fa * fa + fb * fb;
    return -fa / (6.28318530717958647692f * r2);
}
__device__ __forceinline__ float K1f(int a, int b) {
    if (a < 0 || a > 5 || b < 0 || b > 5) return 0.f;
    float fa = (float)a - 2.5f, fb = (float)b - 2.5f;
    float r2 = fa * fa + fb * fb;
    return fb / (6.28318530717958647692f * r2);
}

__global__ __launch_bounds__(256) void k_vel(
    const float* __restrict__ helm, float* __restrict__ vel)
{
    int idx = blockIdx.x * 256 + threadIdx.x;
    if (idx >= NIMG * PIX_T) return;
    int n = idx / PIX_T, pix = idx - n * PIX_T;
    int yy = pix / HWT, xx = pix - yy * HWT;
    const float* phi = helm + (size_t)(n * 2) * PIX_H;
    const float* s   = helm + (size_t)(n * 2 + 1) * PIX_H;
    float sv[7][7];
#pragma unroll
    for (int di = 0; di < 7; ++di) {
        int i = yy + di - 3;
#pragma unroll
        for (int dj = 0; dj < 7; ++dj) {
            int j = xx + dj - 3;
            sv[di][dj] = (i >= 0 && i < 259 && j >= 0 && j < 259) ? s[i * HW + j] : 0.f;
        }
    }
    float ax = 0.5f * (phi[(yy + 1) * HW + xx + 2] - phi[(yy + 1) * HW + xx]);
#pragma unroll
    for (int a = 0; a < 6; ++a)
#pragma unroll
        for (int d = 0; d < 7; ++d) {
            float coef = K0f(a, d) + K0f(a, d - 1);
            ax += 0.5f * coef * sv[a + 1][d];
        }
    float ay = 0.5f * (phi[(yy + 2) * HW + xx + 1] - phi[yy * HW + xx + 1]);
#pragma unroll
    for (int d = 0; d < 7; ++d)
#pragma unroll
        for (int b = 0; b < 6; ++b) {
            float coef = K1f(d, b) + K1f(d - 1, b);
            ay += 0.5f * coef * sv[d][b + 1];
        }
    vel[(size_t)(n * 2) * PIX_T + pix]     = ax;
    vel[(size_t)(n * 2 + 1) * PIX_T + pix] = ay;
}

// ---------------- bilinear warp ---------------------------------------------
__device__ __forceinline__ float bsample(const float* __restrict__ plane,
                                         float px, float py) {
    px = fminf(fmaxf(px, 0.f), 257.f);
    py = fminf(fmaxf(py, 0.f), 257.f);
    float fx = floorf(px), fy = floorf(py);
    int x0 = (int)fx, y0 = (int)fy;
    float wx = px - fx, wy = py - fy;
    int x1 = x0 + 1; if (x1 > 257) x1 = 257;
    int y1 = y0 + 1; if (y1 > 257) y1 = 257;
    const float* r0 = plane + y0 * HWT;
    const float* r1 = plane + y1 * HWT;
    float v00 = r0[x0], v01 = r0[x1], v10 = r1[x0], v11 = r1[x1];
    float tp = v00 + wx * (v01 - v00);
    float bt = v10 + wx * (v11 - v10);
    return tp + wy * (bt - tp);
}

__global__ __launch_bounds__(256) void k_warp(
    const float* __restrict__ src,
    const float* __restrict__ vel,
    float sign,
    const float* __restrict__ tex,
    int mode,                      // 0: sample->out ; 1: out = 1.5*tex - 0.5*sample
    float* __restrict__ out)
{
    int idx = blockIdx.x * 256 + threadIdx.x;
    if (idx >= NIMG * 8 * PIX_T) return;
    int plane_i = idx / PIX_T;
    int pix = idx - plane_i * PIX_T;
    int n = plane_i >> 3;
    int y = pix / HWT, x = pix - y * HWT;
    float vx = vel[(size_t)(n * 2) * PIX_T + pix];
    float vy = vel[(size_t)(n * 2 + 1) * PIX_T + pix];
    const float* plane = src + (size_t)plane_i * PIX_T;
    float v = bsample(plane, (float)x - sign * vx, (float)y - sign * vy);
    if (mode) v = 1.5f * tex[idx] - 0.5f * v;
    out[idx] = v;
}

// ---------------- LayerNorm + MLP residual (in-place on d_out) --------------
// grid (258, 4), block 256.
__global__ __launch_bounds__(256, 2) void k_lnmlp(
    float* __restrict__ out,
    const float* __restrict__ lng, const float* __restrict__ lnb,
    const float* __restrict__ w1, const float* __restrict__ b1,
    const float* __restrict__ w2, const float* __restrict__ b2)
{
    int yy = blockIdx.x, b = blockIdx.y;
    __shared__ __align__(16) float sw1[4096];
    __shared__ __align__(16) float sw2t[4096];  // transposed: [j][j2]
    __shared__ float sb1[64], sb2[64], sg[64], sbt[64];
    int tid = threadIdx.x;
    for (int e = tid; e < 4096; e += 256) {
        sw1[e] = w1[e];
        sw2t[(e & 63) * 64 + (e >> 6)] = w2[e];
    }
    if (tid < 64) { sb1[tid] = b1[tid]; sb2[tid] = b2[tid]; sg[tid] = lng[tid]; sbt[tid] = lnb[tid]; }
    __syncthreads();
    float* base = out + (size_t)b * 64 * PIX_T + (size_t)yy * HWT;
    for (int x = tid; x < HWT; x += 256) {
        float sum = 0.f, sumsq = 0.f;
        for (int k = 0; k < 64; ++k) {
            float v = base[(size_t)k * PIX_T + x];
            sum += v; sumsq += v * v;
        }
        float mu = sum * (1.0f / 64.0f);
        float var = sumsq * (1.0f / 64.0f) - mu * mu;
        float inv = 1.0f / sqrtf(var + 1e-5f);
        float xn[64];
#pragma unroll
        for (int k = 0; k < 64; ++k) {
            float v = base[(size_t)k * PIX_T + x];
            xn[k] = (v - mu) * inv * sg[k] + sbt[k];
        }
        float acc2[64];
#pragma unroll
        for (int j2 = 0; j2 < 64; ++j2) acc2[j2] = 0.f;
        for (int j = 0; j < 64; ++j) {
            float t = sb1[j];
            const float4* wrow = (const float4*)&sw1[j * 64];
#pragma unroll
            for (int k4 = 0; k4 < 16; ++k4) {
                float4 w = wrow[k4];
                t += xn[4 * k4] * w.x + xn[4 * k4 + 1] * w.y
                   + xn[4 * k4 + 2] * w.z + xn[4 * k4 + 3] * w.w;
            }
            float hj = 0.5f * t * (1.0f + erff(t * 0.70710678118654752f));
            const float4* w2row = (const float4*)&sw2t[j * 64];
#pragma unroll
            for (int q = 0; q < 16; ++q) {
                float4 w = w2row[q];
                acc2[4 * q]     += hj * w.x;
                acc2[4 * q + 1] += hj * w.y;
                acc2[4 * q + 2] += hj * w.z;
                acc2[4 * q + 3] += hj * w.w;
            }
        }
#pragma unroll
        for (int j2 = 0; j2 < 64; ++j2)
            base[(size_t)j2 * PIX_T + x] += sb2[j2] + acc2[j2];
    }
}

// ---------------------------------------------------------------------------
extern "C" void kernel_launch(void* const* d_in, const int* in_sizes, int n_in,
                              void* d_out, int out_size, void* d_ws, size_t ws_size,
                              hipStream_t stream) {
    const float* prev       = (const float*)d_in[0];
    const float* next       = (const float*)d_in[1];
    const float* texture    = (const float*)d_in[2];
    const float* mask       = (const float*)d_in[3];
    const float* boundary   = (const float*)d_in[4];
    const float* enc_w      = (const float*)d_in[5];
    const float* enc_b      = (const float*)d_in[6];
    const float* phi_w1     = (const float*)d_in[7];
    const float* phi_g1     = (const float*)d_in[8];
    const float* phi_b1     = (const float*)d_in[9];
    const float* phi_w2     = (const float*)d_in[10];
    const float* phi_g2     = (const float*)d_in[11];
    const float* phi_b2     = (const float*)d_in[12];
    const float* phi_ow     = (const float*)d_in[13];
    const float* phi_ob     = (const float*)d_in[14];
    const float* vor_w1     = (const float*)d_in[15];
    const float* vor_g1     = (const float*)d_in[16];
    const float* vor_b1     = (const float*)d_in[17];
    const float* vor_w2     = (const float*)d_in[18];
    const float* vor_g2     = (const float*)d_in[19];
    const float* vor_b2     = (const float*)d_in[20];
    const float* vor_ow     = (const float*)d_in[21];
    const float* vor_ob     = (const float*)d_in[22];
    const float* phi_weight = (const float*)d_in[23];
    const float* vor_weight = (const float*)d_in[24];
    const float* ln_g       = (const float*)d_in[25];
    const float* ln_b       = (const float*)d_in[26];
    const float* fc1_w      = (const float*)d_in[27];
    const float* fc1_b      = (const float*)d_in[28];
    const float* fc2_w      = (const float*)d_in[29];
    const float* fc2_b      = (const float*)d_in[30];

    float* ws = (float*)d_ws;
    // region plan (floats). peak 56,529,984 floats = 226.1 MB
    float* F_NM = ws + 0;          // 17,305,600
    float* F_A  = ws + 17305600;   // 17,305,600
    float* CORR = ws + 34611200;   // 21,902,400
    float* WT   = ws + 56513600;   // 16,384
    float* H1   = ws + 0;          // 8,652,800  (reuses F_NM after corr)
    float* HELM = ws + 17305600;   // 4,326,400  (reuses F_A)
    float* VEL  = ws + 21632000;   // 4,260,096  (within old F_A region)
    float* F1B  = ws + 34611200;   // 17,040,384 (reuses CORR)
    float* F2B  = ws + 0;          // 17,040,384 (reuses H1)
    float* OUT  = (float*)d_out;

    k_wt<<<dim3(64), dim3(256), 0, stream>>>(enc_w, WT);

    dim3 encg(5, 65, 32);
    k_enc<<<encg, dim3(128), 0, stream>>>(next, mask, WT, enc_b, F_NM);
    k_enc<<<encg, dim3(128), 0, stream>>>(prev, mask, WT, enc_b, F_A);

    dim3 corrg(18, 65, 32);
    k_corr<<<corrg, dim3(128), 0, stream>>>(F_A, F_NM, CORR, 0);
    k_enc<<<encg, dim3(128), 0, stream>>>(prev, boundary, WT, enc_b, F_A);
    k_corr<<<corrg, dim3(128), 0, stream>>>(F_A, F_NM, CORR, 81);

    k_conv1<<<dim3(33, 32), dim3(256), 0, stream>>>(
        CORR, phi_w1, vor_w1, phi_g1, phi_b1, vor_g1, vor_b1, H1);

    k_conv2<<<dim3(260, 32), dim3(256), 0, stream>>>(
        H1, phi_w2, vor_w2, phi_g2, phi_b2, vor_g2, vor_b2,
        phi_ow, phi_ob, vor_ow, vor_ob, phi_weight, vor_weight, HELM);

    int nv = NIMG * PIX_T;
    k_vel<<<dim3((nv + 255) / 256), dim3(256), 0, stream>>>(HELM, VEL);

    int nw = NIMG * 8 * PIX_T;
    int wb = (nw + 255) / 256;
    k_warp<<<dim3(wb), dim3(256), 0, stream>>>(texture, VEL,  1.0f, texture, 0, F1B);
    k_warp<<<dim3(wb), dim3(256), 0, stream>>>(F1B,     VEL, -1.0f, texture, 1, F2B);
    k_warp<<<dim3(wb), dim3(256), 0, stream>>>(F2B,     VEL,  1.0f, texture, 0, OUT);

    k_lnmlp<<<dim3(258, 4), dim3(256), 0, stream>>>(
        OUT, ln_g, ln_b, fc1_w, fc1_b, fc2_w, fc2_b);
}

// Round 4
// 2838.828 us; speedup vs baseline: 1.2267x; 1.0831x over previous
//
#include <hip/hip_runtime.h>
#include <math.h>

// ---------------------------------------------------------------------------
// Model_31009663877809: fluid advection net forward, f32.
// Round 3:
//  - k_conv1 split 3-way over input channels (grid z=3, 9 ci-chunks each)
//    writing raw partial sums; k_h1red sums partials + bn + relu.
//    (was grid-limited at ~16 waves/CU; now LDS-limited at ~24 waves/CU)
//  - k_corr stages channels in 2 passes of 64 (LDS 39->20 KB, occupancy 2x).
// ---------------------------------------------------------------------------

#define NIMG 32          // B*G
#define HW 260
#define HWT 258
#define EG 65            // enc grid
#define EGP (EG*EG)      // 4225
#define PIX_T (HWT*HWT)  // 66564
#define PIX_H (HW*HW)    // 67600
#define H1N 8652800      // 2*32*8*130*130

// ---------------- enc_w transpose: wt[i*128+d] = w[d*128+i] -----------------
__global__ void k_wt(const float* __restrict__ w, float* __restrict__ wt) {
    int e = blockIdx.x * 256 + threadIdx.x;
    if (e < 128 * 128) {
        int d = e >> 7, i = e & 127;
        wt[i * 128 + d] = w[e];
    }
}

// ---------------- encoder: conv 4x4 stride 4, NHWC output -------------------
// grid (5, 65, 32), block 128. Each block: 16 consecutive xo for one (n, yo).
__global__ __launch_bounds__(128) void k_enc(
    const float* __restrict__ src,   // (4,64,260,260)
    const float* __restrict__ mul,   // (4,260,260)
    const float* __restrict__ wt,    // (128i,128d) transposed
    const float* __restrict__ bias,  // (128)
    float* __restrict__ out)         // (32,65,65,128) NHWC
{
    int xt = blockIdx.x;             // 0..4
    int yo = blockIdx.y;             // 0..64
    int n  = blockIdx.z;             // 0..31
    int bi = n >> 3, g = n & 7;
    int xo0 = xt * 16;
    __shared__ __align__(16) float patch[2048];  // [c*4+r][64 cols]
    int tid = threadIdx.x;
    const float* sbase = src + (size_t)(bi * 64 + g * 8) * PIX_H;
    const float* mbase = mul + (size_t)bi * PIX_H;
    int row0 = yo * 4, col0 = xo0 * 4;
    for (int e = tid; e < 2048; e += 128) {
        int c = e >> 8, r = (e >> 6) & 3, col = e & 63;
        int gc = col0 + col;
        float v = 0.f;
        if (gc < HW) {
            int off = (row0 + r) * HW + gc;
            v = sbase[(size_t)c * PIX_H + off] * mbase[off];
        }
        patch[e] = v;
    }
    __syncthreads();
    int d = tid;
    float acc[16];
    float bv = bias[d];
#pragma unroll
    for (int p = 0; p < 16; ++p) acc[p] = bv;
    const float4* p4 = (const float4*)patch;
    for (int j = 0; j < 32; ++j) {   // j = c*4 + ky
        float w0 = wt[(j * 4 + 0) * 128 + d];
        float w1 = wt[(j * 4 + 1) * 128 + d];
        float w2 = wt[(j * 4 + 2) * 128 + d];
        float w3 = wt[(j * 4 + 3) * 128 + d];
#pragma unroll
        for (int p = 0; p < 16; ++p) {
            float4 v = p4[j * 16 + p];
            acc[p] += w0 * v.x + w1 * v.y + w2 * v.z + w3 * v.w;
        }
    }
    size_t ob = ((size_t)(n * EG + yo) * EG + xo0) * 128 + d;
#pragma unroll
    for (int p = 0; p < 16; ++p)
        if (xo0 + p < EG) out[ob + (size_t)p * 128] = acc[p];
}

// ---------------- correlation ------------------------------------------------
// grid (18, 65, 32): bx = dy*2+xt. block 128.
// Channels staged in 2 passes of 64 (LDS 20 KB -> ~7 blocks/CU).
__global__ __launch_bounds__(128) void k_corr(
    const float* __restrict__ f1,  // (32,65,65,128)
    const float* __restrict__ f2,
    float* __restrict__ corr,      // (32,162,65,65)
    int obase)
{
    int bx = blockIdx.x;
    int dy = bx >> 1, xt = bx & 1;
    int y  = blockIdx.y;
    int n  = blockIdx.z;
    int xs = xt ? 33 : 0;
    int nx = xt ? 32 : 33;
    __shared__ __align__(16) float4 s1[33 * 17];  // row stride 17 float4
    __shared__ __align__(16) float4 s2[41 * 17];
    int tid = threadIdx.x;
    const float4* g1 = (const float4*)(f1 + ((size_t)(n * EG + y) * EG + xs) * 128);
    int y2 = y + dy - 4;
    bool yok = (y2 >= 0 && y2 < EG);
    const float4* g2 = (const float4*)(f2 + (yok ? ((size_t)(n * EG + y2) * EG) * 128 : 0));
    int q, xl;
    if (xt) { q = tid >> 5; xl = tid & 31; }
    else    { q = tid / 33; xl = tid - q * 33; }
    int dx0 = q * 3;
    bool act = tid < nx * 3;
    float4 a0 = make_float4(0,0,0,0), a1 = a0, a2 = a0;
    for (int half = 0; half < 2; ++half) {
        int cb = half * 16;
        __syncthreads();
        for (int e = tid; e < nx * 16; e += 128) {
            int r = e >> 4, c4 = e & 15;
            s1[r * 17 + c4] = g1[r * 32 + cb + c4];
        }
        for (int e = tid; e < 41 * 16; e += 128) {
            int r = e >> 4, c4 = e & 15;
            int xg = xs - 4 + r;
            float4 v = make_float4(0.f, 0.f, 0.f, 0.f);
            if (yok && xg >= 0 && xg < EG) v = g2[xg * 32 + cb + c4];
            s2[r * 17 + c4] = v;
        }
        __syncthreads();
        if (act) {
            const float4* r1 = s1 + xl * 17;
            const float4* r2 = s2 + (xl + dx0) * 17;
#pragma unroll 8
            for (int i = 0; i < 16; ++i) {
                float4 a = r1[i];
                float4 b0 = r2[i], b1 = r2[17 + i], b2 = r2[34 + i];
                a0.x += a.x * b0.x; a0.y += a.y * b0.y; a0.z += a.z * b0.z; a0.w += a.w * b0.w;
                a1.x += a.x * b1.x; a1.y += a.y * b1.y; a1.z += a.z * b1.z; a1.w += a.w * b1.w;
                a2.x += a.x * b2.x; a2.y += a.y * b2.y; a2.z += a.z * b2.z; a2.w += a.w * b2.w;
            }
        }
    }
    if (act) {
        float s[3];
        s[0] = (a0.x + a0.y + a0.z + a0.w) * (1.0f / 128.0f);
        s[1] = (a1.x + a1.y + a1.z + a1.w) * (1.0f / 128.0f);
        s[2] = (a2.x + a2.y + a2.z + a2.w) * (1.0f / 128.0f);
#pragma unroll
        for (int m = 0; m < 3; ++m) {
            int o = obase + dy * 9 + dx0 + m;
            corr[(size_t)(n * 162 + o) * EGP + y * EG + xs + xl] = s[m];
        }
    }
}

// ---------------- conv1 (fused up2x 65->130), partial over ci ---------------
// grid (33, 32, 3): yp, n, ci-part. block 256. Each block: 4 rows x 130 x
// 16 oc over 54 input channels (9 chunks of 6). Raw partials (no bn/relu).
__global__ __launch_bounds__(256) void k_conv1(
    const float* __restrict__ corr,   // (32,162,65,65)
    const float* __restrict__ w_phi,  // (8,162,3,3)
    const float* __restrict__ w_vor,
    float* __restrict__ part)         // 3 x (2,32,8,130,130)
{
    int yp = blockIdx.x;              // 0..32
    int n  = blockIdx.y;              // 0..31
    int zp = blockIdx.z;              // 0..2
    int y0 = yp * 4;
    __shared__ float upc[6 * 6 * 132];   // [r6][ci6][132]  19008 B
    __shared__ float wch[16 * 6 * 9];    // [oc16][ci6][9]   3456 B
    __shared__ float s_xw[132];
    __shared__ int   s_xi0[132];
    __shared__ int   s_xi1[132];
    __shared__ float s_yw[6];
    __shared__ int   s_yj0[6];
    __shared__ int   s_yj1[6];
    __shared__ int   s_yv[6];
    int tid = threadIdx.x;
    // interpolation tables (same f32 arithmetic as reference; once per block)
    if (tid < 132) {
        int xu = tid - 1;
        if (xu >= 0 && xu <= 129) {
            float cx = (float)(xu * 64) / 129.0f;
            int i0 = (int)cx;
            int i1 = i0 + 1; if (i1 > 64) i1 = 64;
            s_xw[tid] = cx - (float)i0;
            s_xi0[tid] = i0;
            s_xi1[tid] = i1;
        } else { s_xi0[tid] = -1; s_xi1[tid] = 0; s_xw[tid] = 0.f; }
    }
    if (tid >= 132 && tid < 138) {
        int r = tid - 132;
        int yy = y0 - 1 + r;
        if (yy >= 0 && yy <= 129) {
            float cy = (float)(yy * 64) / 129.0f;
            int i0 = (int)cy;
            int i1 = i0 + 1; if (i1 > 64) i1 = 64;
            s_yw[r] = cy - (float)i0;
            s_yj0[r] = i0;
            s_yj1[r] = i1;
            s_yv[r] = 1;
        } else { s_yw[r] = 0.f; s_yj0[r] = 0; s_yj1[r] = 0; s_yv[r] = 0; }
    }
    int og = tid / 26, xg = tid - og * 26;
    int x0 = xg * 5;
    bool act = (og < 8);
    float acc[2][4][5] = {};
    for (int cc = zp * 9; cc < zp * 9 + 9; ++cc) {
        int cb = cc * 6;
        __syncthreads();
        // fill upc: bilinear interp straight from global corr
        for (int e = tid; e < 4752; e += 256) {
            int r = e / 792, rem = e - r * 792, ci = rem / 132, xx = rem - ci * 132;
            float val = 0.f;
            int xi0 = s_xi0[xx];
            if (s_yv[r] && xi0 >= 0) {
                const float* cp = corr + (size_t)(n * 162 + cb + ci) * EGP;
                int J0 = s_yj0[r] * 65, J1 = s_yj1[r] * 65;
                int xi1 = s_xi1[xx];
                float wxv = s_xw[xx];
                float a0 = __ldg(cp + J0 + xi0), a1 = __ldg(cp + J0 + xi1);
                float b0 = __ldg(cp + J1 + xi0), b1 = __ldg(cp + J1 + xi1);
                float tp = a0 + wxv * (a1 - a0);
                float bt = b0 + wxv * (b1 - b0);
                val = tp + s_yw[r] * (bt - tp);
            }
            upc[e] = val;
        }
        // weights for this ci-chunk
        for (int e = tid; e < 864; e += 256) {
            int oc = e / 54, rem = e - oc * 54, ci = rem / 9, k = rem - ci * 9;
            int t2 = oc >> 3, o = oc & 7;
            wch[e] = (t2 ? w_vor : w_phi)[(o * 162 + cb + ci) * 9 + k];
        }
        __syncthreads();
        if (act) {
            for (int ci = 0; ci < 6; ++ci) {
                float wr[2][9];
#pragma unroll
                for (int p = 0; p < 2; ++p)
#pragma unroll
                    for (int k = 0; k < 9; ++k)
                        wr[p][k] = wch[((og + 8 * p) * 6 + ci) * 9 + k];
#pragma unroll
                for (int r = 0; r < 6; ++r) {
                    float u7[7];
                    const float* up = &upc[(r * 6 + ci) * 132 + x0];
#pragma unroll
                    for (int m = 0; m < 7; ++m) u7[m] = up[m];
#pragma unroll
                    for (int ky = 0; ky < 3; ++ky) {
                        int yi = r - ky;
                        if (yi < 0 || yi > 3) continue;
#pragma unroll
                        for (int p = 0; p < 2; ++p)
#pragma unroll
                            for (int kx = 0; kx < 3; ++kx) {
                                float w = wr[p][ky * 3 + kx];
#pragma unroll
                                for (int xi = 0; xi < 5; ++xi)
                                    acc[p][yi][xi] += w * u7[xi + kx];
                            }
                    }
                }
            }
        }
    }
    if (act) {
        float* pbuf = part + (size_t)zp * H1N;
#pragma unroll
        for (int p = 0; p < 2; ++p) {
            size_t pb = (size_t)((p * 32 + n) * 8 + og) * 16900;
#pragma unroll
            for (int yi = 0; yi < 4; ++yi) {
                int row = y0 + yi;
                if (row < 130) {
#pragma unroll
                    for (int xi = 0; xi < 5; ++xi)
                        pbuf[pb + (size_t)row * 130 + (x0 + xi)] = acc[p][yi][xi];
                }
            }
        }
    }
}

// ---------------- reduce 3 partials + bn + relu -> h1 -----------------------
// float4 grid-stride; H1N/4 = 2,163,200 elements.
__global__ __launch_bounds__(256) void k_h1red(
    const float* __restrict__ part,
    const float* __restrict__ g_phi, const float* __restrict__ b_phi,
    const float* __restrict__ g_vor, const float* __restrict__ b_vor,
    float* __restrict__ h1)
{
    int i4 = blockIdx.x * 256 + threadIdx.x;
    if (i4 >= H1N / 4) return;
    size_t i = (size_t)i4 * 4;
    int c2 = (int)(i / 16900);          // (t2*32+n)*8+o, 0..511
    int o = c2 & 7, t2 = c2 >> 8;
    const float bnsc = 1.0f / sqrtf(1.0f + 1e-5f);
    float gsc = (t2 ? g_vor[o] : g_phi[o]) * bnsc;
    float bia = (t2 ? b_vor[o] : b_phi[o]);
    const float4* p0 = (const float4*)(part);
    const float4* p1 = (const float4*)(part + H1N);
    const float4* p2 = (const float4*)(part + 2 * (size_t)H1N);
    float4 a = p0[i4], b = p1[i4], c = p2[i4];
    float4 r;
    r.x = fmaxf((a.x + b.x + c.x) * gsc + bia, 0.f);
    r.y = fmaxf((a.y + b.y + c.y) * gsc + bia, 0.f);
    r.z = fmaxf((a.z + b.z + c.z) * gsc + bia, 0.f);
    r.w = fmaxf((a.w + b.w + c.w) * gsc + bia, 0.f);
    ((float4*)h1)[i4] = r;
}

// ---------------- conv2 (fused up2x 130->260) + 1x1 head + helm -------------
// grid (260, 32), block 256.
__global__ __launch_bounds__(256) void k_conv2(
    const float* __restrict__ h1,
    const float* __restrict__ w_phi2, const float* __restrict__ w_vor2,
    const float* __restrict__ g_phi2, const float* __restrict__ b_phi2,
    const float* __restrict__ g_vor2, const float* __restrict__ b_vor2,
    const float* __restrict__ ow_phi, const float* __restrict__ ob_phi,
    const float* __restrict__ ow_vor, const float* __restrict__ ob_vor,
    const float* __restrict__ phi_weight, const float* __restrict__ vort_weight,
    float* __restrict__ helm)         // (32,2,260,260)
{
    int y = blockIdx.x, n = blockIdx.y;
    __shared__ float hraw[8320];   // [t2][j4][ci8][130]
    __shared__ float wch[1152];    // [t2][o][ci][9]
    __shared__ float bns[16], bnb[16], owv[16], obv[2], wm[2];
    int tid = threadIdx.x;
    int ylo = y - 1; if (ylo < 0) ylo = 0;
    int R0 = (int)((float)(ylo * 129) / 259.0f);
    for (int e = tid; e < 8320; e += 256) {
        int t2 = e / 4160, rem = e - t2 * 4160;
        int j = rem / 1040, rem2 = rem - j * 1040;
        int ci = rem2 / 130, xx = rem2 - ci * 130;
        int R = R0 + j; if (R > 129) R = 129;
        hraw[e] = h1[(size_t)((t2 * 32 + n) * 8 + ci) * 16900 + R * 130 + xx];
    }
    for (int e = tid; e < 1152; e += 256) {
        int t2 = e / 576, rem = e - t2 * 576;
        int o = rem / 72, rem2 = rem - o * 72;
        int ci = rem2 / 9, k = rem2 - ci * 9;
        wch[e] = (t2 ? w_vor2 : w_phi2)[(o * 8 + ci) * 9 + k];
    }
    if (tid < 16) {
        int t2 = tid >> 3, o = tid & 7;
        bns[tid] = (t2 ? g_vor2[o] : g_phi2[o]) * (1.0f / sqrtf(1.0f + 1e-5f));
        bnb[tid] = (t2 ? b_vor2[o] : b_phi2[o]);
        owv[tid] = (t2 ? ow_vor[o] : ow_phi[o]);
    }
    if (tid == 0) {
        obv[0] = ob_phi[0]; obv[1] = ob_vor[0];
        wm[0] = phi_weight[0]; wm[1] = vort_weight[0] * 260.0f;
    }
    __syncthreads();
    for (int x = tid; x < HW; x += 256) {
        float wy[3]; int rj0[3], rj1[3]; bool vy[3];
#pragma unroll
        for (int ky = 0; ky < 3; ++ky) {
            int yy = y - 1 + ky;
            vy[ky] = (yy >= 0 && yy < HW);
            if (vy[ky]) {
                float cy = (float)(yy * 129) / 259.0f;
                int i0 = (int)cy; wy[ky] = cy - (float)i0;
                int i1 = i0 + 1; if (i1 > 129) i1 = 129;
                rj0[ky] = i0 - R0; rj1[ky] = i1 - R0;
            } else { wy[ky] = 0; rj0[ky] = 0; rj1[ky] = 0; }
        }
        float wxv[3]; int c0[3], c1[3]; bool vx[3];
#pragma unroll
        for (int kx = 0; kx < 3; ++kx) {
            int xxp = x - 1 + kx;
            vx[kx] = (xxp >= 0 && xxp < HW);
            if (vx[kx]) {
                float cx = (float)(xxp * 129) / 259.0f;
                int i0 = (int)cx; wxv[kx] = cx - (float)i0;
                int i1 = i0 + 1; if (i1 > 129) i1 = 129;
                c0[kx] = i0; c1[kx] = i1;
            } else { wxv[kx] = 0; c0[kx] = 0; c1[kx] = 0; }
        }
        float res[2];
#pragma unroll
        for (int t2 = 0; t2 < 2; ++t2) {
            float acc[8] = {0,0,0,0,0,0,0,0};
            for (int ci = 0; ci < 8; ++ci) {
#pragma unroll
                for (int ky = 0; ky < 3; ++ky) {
                    if (!vy[ky]) continue;
                    const float* r0p = &hraw[((t2 * 4 + rj0[ky]) * 8 + ci) * 130];
                    const float* r1p = &hraw[((t2 * 4 + rj1[ky]) * 8 + ci) * 130];
                    float u3[3];
#pragma unroll
                    for (int kx = 0; kx < 3; ++kx) {
                        if (vx[kx]) {
                            float tp = r0p[c0[kx]] + wxv[kx] * (r0p[c1[kx]] - r0p[c0[kx]]);
                            float bt = r1p[c0[kx]] + wxv[kx] * (r1p[c1[kx]] - r1p[c0[kx]]);
                            u3[kx] = tp + wy[ky] * (bt - tp);
                        } else u3[kx] = 0.f;
                    }
#pragma unroll
                    for (int o = 0; o < 8; ++o) {
                        const float* wp = &wch[((t2 * 8 + o) * 8 + ci) * 9 + ky * 3];
                        acc[o] += wp[0] * u3[0] + wp[1] * u3[1] + wp[2] * u3[2];
                    }
                }
            }
            float dot = 0.f;
#pragma unroll
            for (int o = 0; o < 8; ++o) {
                float hv = fmaxf(acc[o] * bns[t2 * 8 + o] + bnb[t2 * 8 + o], 0.f);
                dot += owv[t2 * 8 + o] * hv;
            }
            res[t2] = (dot + obv[t2]) * wm[t2];
        }
        helm[(size_t)(n * 2 + 0) * PIX_H + y * HW + x] = res[0];
        helm[(size_t)(n * 2 + 1) * PIX_H + y * HW + x] = res[1];
    }
}

// ---------------- velocity stencils -----------------------------------------
__device__ __forceinline__ float K0f(int a, int b) {
    if (a < 0 || a > 5 || b < 0 || b > 5) return 0.f;
    float fa = (float)a - 2.5f, fb = (float)b - 2.5f;
    float r2 = fa * fa + fb * fb;
    return -fa / (6.28318530717958647692f * r2);
}
__device__ __forceinline__ float K1f(int a, int b) {
    if (a < 0 || a > 5 || b < 0 || b > 5) return 0.f;
    float fa = (float)a - 2.5f, fb = (float)b - 2.5f;
    float r2 = fa * fa + fb * fb;
    return fb / (6.28318530717958647692f * r2);
}

__global__ __launch_bounds__(256) void k_vel(
    const float* __restrict__ helm, float* __restrict__ vel)
{
    int idx = blockIdx.x * 256 + threadIdx.x;
    if (idx >= NIMG * PIX_T) return;
    int n = idx / PIX_T, pix = idx - n * PIX_T;
    int yy = pix / HWT, xx = pix - yy * HWT;
    const float* phi = helm + (size_t)(n * 2) * PIX_H;
    const float* s   = helm + (size_t)(n * 2 + 1) * PIX_H;
    float sv[7][7];
#pragma unroll
    for (int di = 0; di < 7; ++di) {
        int i = yy + di - 3;
#pragma unroll
        for (int dj = 0; dj < 7; ++dj) {
            int j = xx + dj - 3;
            sv[di][dj] = (i >= 0 && i < 259 && j >= 0 && j < 259) ? s[i * HW + j] : 0.f;
        }
    }
    float ax = 0.5f * (phi[(yy + 1) * HW + xx + 2] - phi[(yy + 1) * HW + xx]);
#pragma unroll
    for (int a = 0; a < 6; ++a)
#pragma unroll
        for (int d = 0; d < 7; ++d) {
            float coef = K0f(a, d) + K0f(a, d - 1);
            ax += 0.5f * coef * sv[a + 1][d];
        }
    float ay = 0.5f * (phi[(yy + 2) * HW + xx + 1] - phi[yy * HW + xx + 1]);
#pragma unroll
    for (int d = 0; d < 7; ++d)
#pragma unroll
        for (int b = 0; b < 6; ++b) {
            float coef = K1f(d, b) + K1f(d - 1, b);
            ay += 0.5f * coef * sv[d][b + 1];
        }
    vel[(size_t)(n * 2) * PIX_T + pix]     = ax;
    vel[(size_t)(n * 2 + 1) * PIX_T + pix] = ay;
}

// ---------------- bilinear warp ---------------------------------------------
__device__ __forceinline__ float bsample(const float* __restrict__ plane,
                                         float px, float py) {
    px = fminf(fmaxf(px, 0.f), 257.f);
    py = fminf(fmaxf(py, 0.f), 257.f);
    float fx = floorf(px), fy = floorf(py);
    int x0 = (int)fx, y0 = (int)fy;
    float wx = px - fx, wy = py - fy;
    int x1 = x0 + 1; if (x1 > 257) x1 = 257;
    int y1 = y0 + 1; if (y1 > 257) y1 = 257;
    const float* r0 = plane + y0 * HWT;
    const float* r1 = plane + y1 * HWT;
    float v00 = r0[x0], v01 = r0[x1], v10 = r1[x0], v11 = r1[x1];
    float tp = v00 + wx * (v01 - v00);
    float bt = v10 + wx * (v11 - v10);
    return tp + wy * (bt - tp);
}

__global__ __launch_bounds__(256) void k_warp(
    const float* __restrict__ src,
    const float* __restrict__ vel,
    float sign,
    const float* __restrict__ tex,
    int mode,                      // 0: sample->out ; 1: out = 1.5*tex - 0.5*sample
    float* __restrict__ out)
{
    int idx = blockIdx.x * 256 + threadIdx.x;
    if (idx >= NIMG * 8 * PIX_T) return;
    int plane_i = idx / PIX_T;
    int pix = idx - plane_i * PIX_T;
    int n = plane_i >> 3;
    int y = pix / HWT, x = pix - y * HWT;
    float vx = vel[(size_t)(n * 2) * PIX_T + pix];
    float vy = vel[(size_t)(n * 2 + 1) * PIX_T + pix];
    const float* plane = src + (size_t)plane_i * PIX_T;
    float v = bsample(plane, (float)x - sign * vx, (float)y - sign * vy);
    if (mode) v = 1.5f * tex[idx] - 0.5f * v;
    out[idx] = v;
}

// ---------------- LayerNorm + MLP residual (in-place on d_out) --------------
// grid (258, 4), block 256.
__global__ __launch_bounds__(256, 2) void k_lnmlp(
    float* __restrict__ out,
    const float* __restrict__ lng, const float* __restrict__ lnb,
    const float* __restrict__ w1, const float* __restrict__ b1,
    const float* __restrict__ w2, const float* __restrict__ b2)
{
    int yy = blockIdx.x, b = blockIdx.y;
    __shared__ __align__(16) float sw1[4096];
    __shared__ __align__(16) float sw2t[4096];  // transposed: [j][j2]
    __shared__ float sb1[64], sb2[64], sg[64], sbt[64];
    int tid = threadIdx.x;
    for (int e = tid; e < 4096; e += 256) {
        sw1[e] = w1[e];
        sw2t[(e & 63) * 64 + (e >> 6)] = w2[e];
    }
    if (tid < 64) { sb1[tid] = b1[tid]; sb2[tid] = b2[tid]; sg[tid] = lng[tid]; sbt[tid] = lnb[tid]; }
    __syncthreads();
    float* base = out + (size_t)b * 64 * PIX_T + (size_t)yy * HWT;
    for (int x = tid; x < HWT; x += 256) {
        float sum = 0.f, sumsq = 0.f;
        for (int k = 0; k < 64; ++k) {
            float v = base[(size_t)k * PIX_T + x];
            sum += v; sumsq += v * v;
        }
        float mu = sum * (1.0f / 64.0f);
        float var = sumsq * (1.0f / 64.0f) - mu * mu;
        float inv = 1.0f / sqrtf(var + 1e-5f);
        float xn[64];
#pragma unroll
        for (int k = 0; k < 64; ++k) {
            float v = base[(size_t)k * PIX_T + x];
            xn[k] = (v - mu) * inv * sg[k] + sbt[k];
        }
        float acc2[64];
#pragma unroll
        for (int j2 = 0; j2 < 64; ++j2) acc2[j2] = 0.f;
        for (int j = 0; j < 64; ++j) {
            float t = sb1[j];
            const float4* wrow = (const float4*)&sw1[j * 64];
#pragma unroll
            for (int k4 = 0; k4 < 16; ++k4) {
                float4 w = wrow[k4];
                t += xn[4 * k4] * w.x + xn[4 * k4 + 1] * w.y
                   + xn[4 * k4 + 2] * w.z + xn[4 * k4 + 3] * w.w;
            }
            float hj = 0.5f * t * (1.0f + erff(t * 0.70710678118654752f));
            const float4* w2row = (const float4*)&sw2t[j * 64];
#pragma unroll
            for (int q = 0; q < 16; ++q) {
                float4 w = w2row[q];
                acc2[4 * q]     += hj * w.x;
                acc2[4 * q + 1] += hj * w.y;
                acc2[4 * q + 2] += hj * w.z;
                acc2[4 * q + 3] += hj * w.w;
            }
        }
#pragma unroll
        for (int j2 = 0; j2 < 64; ++j2)
            base[(size_t)j2 * PIX_T + x] += sb2[j2] + acc2[j2];
    }
}

// ---------------------------------------------------------------------------
extern "C" void kernel_launch(void* const* d_in, const int* in_sizes, int n_in,
                              void* d_out, int out_size, void* d_ws, size_t ws_size,
                              hipStream_t stream) {
    const float* prev       = (const float*)d_in[0];
    const float* next       = (const float*)d_in[1];
    const float* texture    = (const float*)d_in[2];
    const float* mask       = (const float*)d_in[3];
    const float* boundary   = (const float*)d_in[4];
    const float* enc_w      = (const float*)d_in[5];
    const float* enc_b      = (const float*)d_in[6];
    const float* phi_w1     = (const float*)d_in[7];
    const float* phi_g1     = (const float*)d_in[8];
    const float* phi_b1     = (const float*)d_in[9];
    const float* phi_w2     = (const float*)d_in[10];
    const float* phi_g2     = (const float*)d_in[11];
    const float* phi_b2     = (const float*)d_in[12];
    const float* phi_ow     = (const float*)d_in[13];
    const float* phi_ob     = (const float*)d_in[14];
    const float* vor_w1     = (const float*)d_in[15];
    const float* vor_g1     = (const float*)d_in[16];
    const float* vor_b1     = (const float*)d_in[17];
    const float* vor_w2     = (const float*)d_in[18];
    const float* vor_g2     = (const float*)d_in[19];
    const float* vor_b2     = (const float*)d_in[20];
    const float* vor_ow     = (const float*)d_in[21];
    const float* vor_ob     = (const float*)d_in[22];
    const float* phi_weight = (const float*)d_in[23];
    const float* vor_weight = (const float*)d_in[24];
    const float* ln_g       = (const float*)d_in[25];
    const float* ln_b       = (const float*)d_in[26];
    const float* fc1_w      = (const float*)d_in[27];
    const float* fc1_b      = (const float*)d_in[28];
    const float* fc2_w      = (const float*)d_in[29];
    const float* fc2_b      = (const float*)d_in[30];

    float* ws = (float*)d_ws;
    // region plan (floats). peak ~226.1 MB
    float* F_NM = ws + 0;          // 17,305,600
    float* F_A  = ws + 17305600;   // 17,305,600
    float* CORR = ws + 34611200;   // 21,902,400
    float* WT   = ws + 56513600;   // 16,384
    float* PART = ws + 0;          // 3 x 8,652,800 = 25,958,400 (reuses F_NM/F_A)
    float* H1   = ws + 25958400;   // 8,652,800 (fits exactly before CORR)
    float* HELM = ws + 17305600;   // 4,326,400 (overlaps old PART tail? no:
                                   //  HELM written by conv2 after PART dead)
    float* VEL  = ws + 21632000;   // 4,260,096
    float* F1B  = ws + 34611200;   // 17,040,384 (reuses CORR)
    float* F2B  = ws + 0;          // 17,040,384
    float* OUT  = (float*)d_out;

    k_wt<<<dim3(64), dim3(256), 0, stream>>>(enc_w, WT);

    dim3 encg(5, 65, 32);
    k_enc<<<encg, dim3(128), 0, stream>>>(next, mask, WT, enc_b, F_NM);
    k_enc<<<encg, dim3(128), 0, stream>>>(prev, mask, WT, enc_b, F_A);

    dim3 corrg(18, 65, 32);
    k_corr<<<corrg, dim3(128), 0, stream>>>(F_A, F_NM, CORR, 0);
    k_enc<<<encg, dim3(128), 0, stream>>>(prev, boundary, WT, enc_b, F_A);
    k_corr<<<corrg, dim3(128), 0, stream>>>(F_A, F_NM, CORR, 81);

    k_conv1<<<dim3(33, 32, 3), dim3(256), 0, stream>>>(
        CORR, phi_w1, vor_w1, PART);
    k_h1red<<<dim3((H1N / 4 + 255) / 256), dim3(256), 0, stream>>>(
        PART, phi_g1, phi_b1, vor_g1, vor_b1, H1);

    k_conv2<<<dim3(260, 32), dim3(256), 0, stream>>>(
        H1, phi_w2, vor_w2, phi_g2, phi_b2, vor_g2, vor_b2,
        phi_ow, phi_ob, vor_ow, vor_ob, phi_weight, vor_weight, HELM);

    int nv = NIMG * PIX_T;
    k_vel<<<dim3((nv + 255) / 256), dim3(256), 0, stream>>>(HELM, VEL);

    int nw = NIMG * 8 * PIX_T;
    int wb = (nw + 255) / 256;
    k_warp<<<dim3(wb), dim3(256), 0, stream>>>(texture, VEL,  1.0f, texture, 0, F1B);
    k_warp<<<dim3(wb), dim3(256), 0, stream>>>(F1B,     VEL, -1.0f, texture, 1, F2B);
    k_warp<<<dim3(wb), dim3(256), 0, stream>>>(F2B,     VEL,  1.0f, texture, 0, OUT);

    k_lnmlp<<<dim3(258, 4), dim3(256), 0, stream>>>(
        OUT, ln_g, ln_b, fc1_w, fc1_b, fc2_w, fc2_b);
}